// Round 4
// baseline (2441.535 us; speedup 1.0000x reference)
//
#include <hip/hip_runtime.h>
#include <math.h>

#define DI static __device__ __forceinline__

DI float eluf(float x){ return x > 0.f ? x : expm1f(x); }
DI float lreluf(float x){ return x > 0.f ? x : 0.2f*x; }
DI float sigmf(float x){ return 1.f/(1.f+expf(-x)); }

constexpr int N=200, E=3200, HID=64, NH=16, OUTD=128, CAT=2048, SEQD=2240;

// ---- per-graph f32 scratch offsets (in floats) ----
constexpr int OH0   = 0;                 // [N,HID]   elu(feat@W_h)
constexpr int OWH   = OH0 + N*HID;       // [NH,N,OUTD] Wh per head
constexpr int OASN  = OWH + NH*N*OUTD;   // [NH,N]    Wh@a_src
constexpr int OADN  = OASN + NH*N;       // [NH,N]    Wh@a_dst
constexpr int OH1   = OADN + NH*N;       // [N,CAT]   concat head outputs (pre-pool scale)
constexpr int OXW1  = OH1 + N*CAT;       // [N]
constexpr int OXW2  = OXW1 + 256;        // [N]
constexpr int OEW1  = OXW2 + 256;        // [E]
constexpr int OS1   = OEW1 + E;          // [E]
constexpr int ODEG1 = OS1 + E;           // [N]
constexpr int OSS1  = ODEG1 + 256;       // [N]
constexpr int ONS1  = OSS1 + 256;        // [N]
constexpr int OWH2  = ONS1 + 256;        // [N,OUTD]
constexpr int OAS2  = OWH2 + N*OUTD;     // [N]
constexpr int OAD2  = OAS2 + 256;        // [N]
constexpr int OEWV  = OAD2 + 256;        // [E]  RAW e1cat@v_e
constexpr int OH2B  = OEWV + E;          // [N,OUTD]
constexpr int OXS2  = OH2B + N*OUTD;     // [N]
constexpr int OXD2  = OXS2 + 256;        // [N]
constexpr int OEW2  = OXD2 + 256;        // [E]
constexpr int OS2   = OEW2 + E;          // [E]
constexpr int ODEG2 = OS2 + E;           // [N]
constexpr int OSS2  = ODEG2 + 256;       // [N]
constexpr int ONS2  = OSS2 + 256;        // [N]
constexpr int OGATE = ONS2 + 256;        // [N]
constexpr int PGF   = OGATE + 256;       // per-graph float count
constexpr int GLOBF = 8576;              // we_ae(1024)+v_e(2048)+y0(512)+y1(512)+xseq(4480)
constexpr int TOTF  = GLOBF + 2*PGF;

// ---- static device scratch: independent of ws_size ----
__device__ float G_F[TOTF];
__device__ int   G_PIDX[2*N*N];

DI float* gf(int g){ return G_F + GLOBF + (size_t)g*PGF; }
DI float* gwe_ae(){ return G_F; }
DI float* gv_e(){ return G_F + 1024; }
DI float* gy0(){ return G_F + 3072; }
DI float* gy1(){ return G_F + 3584; }
DI float* gxseq(){ return G_F + 4096; }
DI int*   gpidx(int g){ return G_PIDX + g*N*N; }

struct GraphIn {
  const float *feat, *eattr, *adj, *n2n;
  const int   *eidx;
};

struct Params {
  GraphIn g[2];
  const float *W_h, *W_gat, *a_src, *a_dst, *a_e, *We_gat;
  const float *W_out, *ao_src, *ao_dst, *ao_e, *We_out;
  const float *ep1_w, *ep1_b, *ep2_w, *ep2_b;
  const float *g1_w, *g1_b, *g2_w, *g2_b, *g3_w, *g3_b;
  const float *Wih0, *Whh0, *b0, *Wih1, *Whh1, *b1, *fc_w, *fc_b;
  float *out;
};

// ---------------- zero ALL scratch; pairIdx=-1 ----------------
__global__ void k_zero(){
  int idx = blockIdx.x*256 + threadIdx.x;
  if (idx < TOTF) G_F[idx] = 0.f;
  if (idx < 2*N*N) G_PIDX[idx] = -1;
}

// ---------------- precontract We@a_e vectors ----------------
__global__ void k_pre(Params P){
  int idx = blockIdx.x*256 + threadIdx.x;
  if (idx < NH*HID){
    int h = idx/HID, c = idx%HID;
    const float* W = P.We_gat + (size_t)(h*HID + c)*OUTD;
    const float* a = P.a_e + h*OUTD;
    float acc = 0.f;
    for (int o=0;o<OUTD;o++) acc += W[o]*a[o];
    gwe_ae()[idx] = acc;
  } else if (idx < NH*HID + CAT){
    int c = idx - NH*HID;
    const float* W = P.We_out + (size_t)c*OUTD;
    float acc = 0.f;
    for (int o=0;o<OUTD;o++) acc += W[o]*P.ao_e[o];
    gv_e()[c] = acc;
  }
}

// ---------------- h0 = elu(feat @ W_h) ----------------
__global__ void k_h0(Params P){
  int idx = blockIdx.x*256 + threadIdx.x;
  if (idx >= 2*N*HID) return;
  int g = idx/(N*HID), r = idx%(N*HID), n = r/HID, c = r%HID;
  const float* feat = P.g[g].feat;
  float acc = 0.f;
  for (int k=0;k<HID;k++) acc += feat[n*HID+k]*P.W_h[k*HID+c];
  gf(g)[OH0 + n*HID + c] = eluf(acc);
}

// ---------------- Wh[h] = h0 @ W_gat[h] ----------------
__global__ void k_Wh(Params P){
  int n = blockIdx.x, h = blockIdx.y, g = blockIdx.z, o = threadIdx.x;
  __shared__ float hs[HID];
  float* f = gf(g);
  if (o < HID) hs[o] = f[OH0 + n*HID + o];
  __syncthreads();
  const float* W = P.W_gat + (size_t)h*HID*OUTD + o;
  float acc = 0.f;
  for (int c=0;c<HID;c++) acc += hs[c]*W[(size_t)c*OUTD];
  f[OWH + ((size_t)h*N + n)*OUTD + o] = acc;
}

// ---------------- asn/adn = Wh @ a_src / a_dst ----------------
__global__ void k_asad(Params P){
  int h = blockIdx.x, g = blockIdx.y;
  float* f = gf(g);
  for (int n = threadIdx.x; n < N; n += 256){
    const float* wh = f + OWH + ((size_t)h*N + n)*OUTD;
    float s=0.f, d=0.f;
    for (int o=0;o<OUTD;o++){
      float v = wh[o];
      s += v*P.a_src[h*OUTD+o];
      d += v*P.a_dst[h*OUTD+o];
    }
    f[OASN + h*N + n] = s;
    f[OADN + h*N + n] = d;
  }
}

// ---------------- GAT layer 1: row softmax + aggregate (per head) ----------------
__global__ void k_att1(Params P){
  int n = blockIdx.x, h = blockIdx.y, g = blockIdx.z, tid = threadIdx.x;
  __shared__ float z[N];
  __shared__ float red[128];
  float* f = gf(g);
  const float* adj = P.g[g].adj;
  const float* n2n = P.g[g].n2n;
  const float* weae = gwe_ae() + h*HID;
  float asn = f[OASN + h*N + n];
  const float* adn = f + OADN + h*N;
  for (int j = tid; j < N; j += 128){
    float a = adj[n*N + j];
    float zz;
    if (a > 0.f){
      const float* row = n2n + (size_t)(n*N + j)*HID;
      float ee = 0.f;
      for (int c=0;c<HID;c++) ee += row[c]*weae[c];
      zz = lreluf(asn + adn[j] + ee);
    } else zz = -1e9f;
    z[j] = zz;
  }
  __syncthreads();
  float m = -3e38f;
  for (int j = tid; j < N; j += 128) m = fmaxf(m, z[j]);
  red[tid] = m; __syncthreads();
  for (int s=64;s>0;s>>=1){ if (tid<s) red[tid]=fmaxf(red[tid],red[tid+s]); __syncthreads(); }
  m = red[0]; __syncthreads();
  float ssum = 0.f;
  for (int j = tid; j < N; j += 128){ float e = expf(z[j]-m); z[j]=e; ssum += e; }
  red[tid] = ssum; __syncthreads();
  for (int s=64;s>0;s>>=1){ if (tid<s) red[tid]+=red[tid+s]; __syncthreads(); }
  float inv = 1.f/red[0]; __syncthreads();
  const float* wh = f + OWH + (size_t)h*N*OUTD;
  float acc = 0.f;
  for (int j=0;j<N;j++){
    float w = z[j];
    if (w != 0.f) acc += w * wh[(size_t)j*OUTD + tid];
  }
  f[OH1 + (size_t)n*CAT + h*OUTD + tid] = eluf(acc*inv);
}

// ---- fused edge dots: ew1[e], ewv_raw[e]; e1cat recomputed on the fly ----
__global__ void k_edot1(Params P){
  int e = blockIdx.x, g = blockIdx.y, tid = threadIdx.x;   // 128 threads
  __shared__ float es[HID];
  __shared__ float r1[128], r2[128];
  const float* ea = P.g[g].eattr + (size_t)e*HID;
  if (tid < HID) es[tid] = ea[tid];
  __syncthreads();
  float a1 = 0.f, a2 = 0.f;
  for (int h=0; h<NH; ++h){
    const float* W = P.We_gat + (size_t)(h*HID)*OUTD + tid;
    float t = 0.f;
    for (int c=0;c<HID;c++) t += es[c]*W[(size_t)c*OUTD];
    t = eluf(t);
    a1 += t * P.ep1_w[2*CAT + h*OUTD + tid];
    a2 += t * gv_e()[h*OUTD + tid];
  }
  r1[tid]=a1; r2[tid]=a2; __syncthreads();
  for (int s=64;s>0;s>>=1){ if (tid<s){ r1[tid]+=r1[tid+s]; r2[tid]+=r2[tid+s]; } __syncthreads(); }
  if (tid==0){ float* f=gf(g); f[OEW1+e]=r1[0]; f[OEWV+e]=r2[0]; }
}

// ---------------- pool1 node dots ----------------
__global__ void k_xw1(Params P){
  int n = blockIdx.x, wch = blockIdx.y, g = blockIdx.z, tid = threadIdx.x;
  __shared__ float sb[256];
  float* f = gf(g);
  const float* x = f + OH1 + (size_t)n*CAT;
  const float* w = P.ep1_w + wch*CAT;
  float acc = 0.f;
  for (int c = tid; c < CAT; c += 256) acc += x[c]*w[c];
  sb[tid] = acc; __syncthreads();
  for (int s=128;s>0;s>>=1){ if (tid<s) sb[tid]+=sb[tid+s]; __syncthreads(); }
  if (tid==0) f[(wch? OXW2:OXW1) + n] = sb[0];
}

// ---------------- pool1 edge scores + segment sums ----------------
__global__ void k_s1(Params P){
  int e = blockIdx.x*256 + threadIdx.x, g = blockIdx.y;
  if (e >= E) return;
  float* f = gf(g);
  const int* ei = P.g[g].eidx;
  int s = ei[e], d = ei[E+e];
  float v = sigmf(f[OXW1+s] + f[OXW2+d] + f[OEW1+e] + P.ep1_b[0]);
  f[OS1+e] = v;
  atomicAdd(&f[OSS1+s], v);
  atomicAdd(&f[ODEG1+s], 1.f);
}

__global__ void k_ns(int odeg, int oss, int ons){
  int g = blockIdx.y, n = threadIdx.x;
  if (n < N){ float* f = gf(g); f[ons+n] = f[oss+n]/(f[odeg+n]+1e-6f); }
}

// ---------------- pairIdx: last edge wins ----------------
__global__ void k_pairs(Params P){
  int e = blockIdx.x*256 + threadIdx.x, g = blockIdx.y;
  if (e >= E) return;
  const int* ei = P.g[g].eidx;
  atomicMax(&gpidx(g)[ei[e]*N + ei[E+e]], e);
}

// ---------------- global attention pool ----------------
__global__ void k_gpool_gate(Params P, int xoff, int D, int scaleoff, const float* w, const float* b){
  int n = blockIdx.x, g = blockIdx.y, tid = threadIdx.x;
  __shared__ float sb[256];
  float* f = gf(g);
  const float* x = f + xoff + (size_t)n*D;
  float acc = 0.f;
  for (int c = tid; c < D; c += 256) acc += x[c]*w[c];
  sb[tid] = acc; __syncthreads();
  for (int s=128;s>0;s>>=1){ if (tid<s) sb[tid]+=sb[tid+s]; __syncthreads(); }
  if (tid==0){
    float sc = scaleoff>=0 ? f[scaleoff+n] : 1.f;
    f[OGATE+n] = sigmf(sb[0]*sc + b[0]);
  }
}

__global__ void k_gpool_out(Params P, int xoff, int D, int scaleoff, int outoff){
  int g = blockIdx.x, tid = threadIdx.x;
  __shared__ float att[N];
  __shared__ float sb[256];
  float* f = gf(g);
  float m = -3e38f;
  for (int n = tid; n < N; n += 256) m = fmaxf(m, f[OGATE+n]);
  sb[tid] = m; __syncthreads();
  for (int s=128;s>0;s>>=1){ if (tid<s) sb[tid]=fmaxf(sb[tid],sb[tid+s]); __syncthreads(); }
  m = sb[0]; __syncthreads();
  float ss = 0.f;
  for (int n = tid; n < N; n += 256){ float e = expf(f[OGATE+n]-m); att[n]=e; ss += e; }
  sb[tid] = ss; __syncthreads();
  for (int s=128;s>0;s>>=1){ if (tid<s) sb[tid]+=sb[tid+s]; __syncthreads(); }
  float inv = 1.f/sb[0]; __syncthreads();
  for (int n = tid; n < N; n += 256){
    float sc = scaleoff>=0 ? f[scaleoff+n] : 1.f;
    att[n] *= inv*sc;
  }
  __syncthreads();
  const float* x = f + xoff;
  for (int c = tid; c < D; c += 256){
    float acc = 0.f;
    for (int n=0;n<N;n++) acc += att[n]*x[(size_t)n*D + c];
    gxseq()[g*SEQD + outoff + c] = acc;
  }
}

// ---------------- Wh2 = (h1cat @ W_out) * ns1 ----------------
__global__ void k_Wh2(Params P){
  int n = blockIdx.x, g = blockIdx.y, tid = threadIdx.x;
  __shared__ float hrow[128];
  float* f = gf(g);
  const float* x = f + OH1 + (size_t)n*CAT;
  float ns = f[ONS1+n];
  float acc = 0.f;
  for (int c0=0;c0<CAT;c0+=128){
    __syncthreads();
    hrow[tid] = x[c0+tid];
    __syncthreads();
    const float* W = P.W_out + (size_t)c0*OUTD + tid;
    for (int cc=0;cc<128;cc++) acc += hrow[cc]*W[(size_t)cc*OUTD];
  }
  f[OWH2 + (size_t)n*OUTD + tid] = acc*ns;
}

__global__ void k_asad2(Params P){
  int g = blockIdx.x;
  float* f = gf(g);
  for (int n = threadIdx.x; n < N; n += 256){
    const float* wh = f + OWH2 + (size_t)n*OUTD;
    float s=0.f, d=0.f;
    for (int o=0;o<OUTD;o++){
      float v = wh[o];
      s += v*P.ao_src[o];
      d += v*P.ao_dst[o];
    }
    f[OAS2+n]=s; f[OAD2+n]=d;
  }
}

// ---------------- GAT layer 2 ----------------
__global__ void k_att2(Params P){
  int n = blockIdx.x, g = blockIdx.y, tid = threadIdx.x;
  __shared__ float z[N];
  __shared__ float red[128];
  float* f = gf(g);
  const float* adj = P.g[g].adj;
  const int* pidx = gpidx(g);
  float asn = f[OAS2+n];
  const float* adn = f + OAD2;
  for (int j = tid; j < N; j += 128){
    float a = adj[n*N + j];
    float zz;
    if (a > 0.f){
      int p = pidx[n*N + j];
      float ee = (p >= 0) ? f[OEWV+p]*f[OS1+p] : 0.f;
      zz = lreluf(asn + adn[j] + ee);
    } else zz = -1e9f;
    z[j] = zz;
  }
  __syncthreads();
  float m = -3e38f;
  for (int j = tid; j < N; j += 128) m = fmaxf(m, z[j]);
  red[tid] = m; __syncthreads();
  for (int s=64;s>0;s>>=1){ if (tid<s) red[tid]=fmaxf(red[tid],red[tid+s]); __syncthreads(); }
  m = red[0]; __syncthreads();
  float ssum = 0.f;
  for (int j = tid; j < N; j += 128){ float e = expf(z[j]-m); z[j]=e; ssum += e; }
  red[tid] = ssum; __syncthreads();
  for (int s=64;s>0;s>>=1){ if (tid<s) red[tid]+=red[tid+s]; __syncthreads(); }
  float inv = 1.f/red[0]; __syncthreads();
  const float* wh = f + OWH2;
  float acc = 0.f;
  for (int j=0;j<N;j++){
    float w = z[j];
    if (w != 0.f) acc += w * wh[(size_t)j*OUTD + tid];
  }
  f[OH2B + (size_t)n*OUTD + tid] = acc*inv;   // concat=False: no elu
}

// ---- fused e2 + ew2 ----
__global__ void k_e2f(Params P){
  int e = blockIdx.x, g = blockIdx.y, tid = threadIdx.x;   // 128 threads
  __shared__ float es[HID];
  __shared__ float tcol[128];
  __shared__ float red[128];
  float* f = gf(g);
  const float* ea = P.g[g].eattr + (size_t)e*HID;
  if (tid < HID) es[tid] = ea[tid];
  __syncthreads();
  float acc = 0.f;
  for (int h=0; h<NH; ++h){
    const float* W1 = P.We_gat + (size_t)(h*HID)*OUTD + tid;
    float t = 0.f;
    for (int c=0;c<HID;c++) t += es[c]*W1[(size_t)c*OUTD];
    t = eluf(t);
    __syncthreads();
    tcol[tid] = t;
    __syncthreads();
    const float* W2 = P.We_out + (size_t)(h*OUTD)*OUTD + tid;
    for (int o=0;o<OUTD;o++) acc += tcol[o]*W2[(size_t)o*OUTD];
  }
  float v = eluf(f[OS1+e]*acc);
  red[tid] = v * P.ep2_w[2*OUTD + tid];
  __syncthreads();
  for (int s=64;s>0;s>>=1){ if (tid<s) red[tid]+=red[tid+s]; __syncthreads(); }
  if (tid==0) f[OEW2+e] = red[0];
}

// ---------------- pool2 node dots ----------------
__global__ void k_xsd2(Params P){
  int g = blockIdx.x;
  float* f = gf(g);
  for (int n = threadIdx.x; n < N; n += 256){
    const float* x = f + OH2B + (size_t)n*OUTD;
    float s=0.f, d=0.f;
    for (int k=0;k<OUTD;k++){
      float v = x[k];
      s += v*P.ep2_w[k];
      d += v*P.ep2_w[OUTD+k];
    }
    f[OXS2+n]=s; f[OXD2+n]=d;
  }
}

__global__ void k_s2(Params P){
  int e = blockIdx.x*256 + threadIdx.x, g = blockIdx.y;
  if (e >= E) return;
  float* f = gf(g);
  const int* ei = P.g[g].eidx;
  int s = ei[e], d = ei[E+e];
  float v = sigmf(f[OXS2+s] + f[OXD2+d] + f[OEW2+e] + P.ep2_b[0]);
  f[OS2+e] = v;
  atomicAdd(&f[OSS2+s], v);
  atomicAdd(&f[ODEG2+s], 1.f);
}

// ---------------- bidirectional LSTM layer ----------------
__global__ void k_lstm(Params P, int layer){
  int d = blockIdx.x, tid = threadIdx.x;
  const float* Wih = layer ? P.Wih1 : P.Wih0;
  const float* Whh = layer ? P.Whh1 : P.Whh0;
  const float* bb  = layer ? P.b1   : P.b0;
  const float* xin = layer ? gy0() : gxseq();
  float* yout = layer ? gy1() : gy0();
  int Din = layer ? 256 : SEQD;
  __shared__ float h[128], c[128], gbuf[512];
  if (tid < 128){ h[tid]=0.f; c[tid]=0.f; }
  __syncthreads();
  for (int s=0;s<2;s++){
    int t = (d==0) ? s : 1-s;
    const float* x = xin + t*Din;
    const float* Wr = Wih + ((size_t)d*512 + tid)*Din;
    float acc = bb[d*512 + tid];
    for (int k=0;k<Din;k++) acc += x[k]*Wr[k];
    const float* Ur = Whh + ((size_t)d*512 + tid)*128;
    for (int k=0;k<128;k++) acc += h[k]*Ur[k];
    gbuf[tid] = acc;
    __syncthreads();
    if (tid < 128){
      float ii = sigmf(gbuf[tid]);
      float ff = sigmf(gbuf[128+tid]);
      float gg = tanhf(gbuf[256+tid]);
      float oo = sigmf(gbuf[384+tid]);
      float cn = ff*c[tid] + ii*gg;
      c[tid] = cn;
      float hn = oo*tanhf(cn);
      h[tid] = hn;
      yout[t*256 + d*128 + tid] = hn;
    }
    __syncthreads();
  }
}

// ---------------- final FC + softmax ----------------
__global__ void k_final(Params P){
  int tid = threadIdx.x;
  __shared__ float sb[256], sb2[256];
  const float* x = gy1() + 256;  // x[-1]
  sb[tid]  = x[tid]*P.fc_w[tid*2+0];
  sb2[tid] = x[tid]*P.fc_w[tid*2+1];
  __syncthreads();
  for (int s=128;s>0;s>>=1){ if (tid<s){ sb[tid]+=sb[tid+s]; sb2[tid]+=sb2[tid+s]; } __syncthreads(); }
  if (tid==0){
    float l0 = sb[0] + P.fc_b[0];
    float l1 = sb2[0] + P.fc_b[1];
    float m = fmaxf(l0,l1);
    float e0 = expf(l0-m), e1 = expf(l1-m), inv = 1.f/(e0+e1);
    P.out[0] = e0*inv;
    P.out[1] = e1*inv;
  }
}

extern "C" void kernel_launch(void* const* d_in, const int* in_sizes, int n_in,
                              void* d_out, int out_size, void* d_ws, size_t ws_size,
                              hipStream_t stream){
  Params P;
  for (int g=0; g<2; ++g){
    int b = g*5;
    P.g[g].feat  = (const float*)d_in[b+0];
    P.g[g].eidx  = (const int*)d_in[b+1];
    P.g[g].eattr = (const float*)d_in[b+2];
    P.g[g].adj   = (const float*)d_in[b+3];
    P.g[g].n2n   = (const float*)d_in[b+4];
  }
  P.W_h   = (const float*)d_in[10];
  P.W_gat = (const float*)d_in[11];
  P.a_src = (const float*)d_in[12];
  P.a_dst = (const float*)d_in[13];
  P.a_e   = (const float*)d_in[14];
  P.We_gat= (const float*)d_in[15];
  P.W_out = (const float*)d_in[16];
  P.ao_src= (const float*)d_in[17];
  P.ao_dst= (const float*)d_in[18];
  P.ao_e  = (const float*)d_in[19];
  P.We_out= (const float*)d_in[20];
  P.ep1_w = (const float*)d_in[21];
  P.ep1_b = (const float*)d_in[22];
  P.ep2_w = (const float*)d_in[23];
  P.ep2_b = (const float*)d_in[24];
  P.g1_w  = (const float*)d_in[25];
  P.g1_b  = (const float*)d_in[26];
  P.g2_w  = (const float*)d_in[27];
  P.g2_b  = (const float*)d_in[28];
  P.g3_w  = (const float*)d_in[29];
  P.g3_b  = (const float*)d_in[30];
  P.Wih0  = (const float*)d_in[31];
  P.Whh0  = (const float*)d_in[32];
  P.b0    = (const float*)d_in[33];
  P.Wih1  = (const float*)d_in[34];
  P.Whh1  = (const float*)d_in[35];
  P.b1    = (const float*)d_in[36];
  P.fc_w  = (const float*)d_in[37];
  P.fc_b  = (const float*)d_in[38];
  P.out   = (float*)d_out;

  // ---- graph stages (both graphs in each kernel via grid dim) ----
  k_zero <<<dim3((TOTF+255)/256 + 1), 256, 0, stream>>>();
  k_pre  <<<dim3((NH*HID+CAT+255)/256), 256, 0, stream>>>(P);
  k_h0   <<<dim3((2*N*HID+255)/256), 256, 0, stream>>>(P);
  k_gpool_gate<<<dim3(N,2), 256, 0, stream>>>(P, OH0, HID, -1, P.g1_w, P.g1_b);
  k_gpool_out <<<dim3(2),   256, 0, stream>>>(P, OH0, HID, -1, 0);
  k_Wh   <<<dim3(N,NH,2), 128, 0, stream>>>(P);
  k_asad <<<dim3(NH,2),   256, 0, stream>>>(P);
  k_att1 <<<dim3(N,NH,2), 128, 0, stream>>>(P);
  k_edot1<<<dim3(E,2),    128, 0, stream>>>(P);
  k_xw1  <<<dim3(N,2,2),  256, 0, stream>>>(P);
  k_s1   <<<dim3((E+255)/256,2), 256, 0, stream>>>(P);
  k_ns   <<<dim3(1,2),    256, 0, stream>>>(ODEG1, OSS1, ONS1);
  k_gpool_gate<<<dim3(N,2), 256, 0, stream>>>(P, OH1, CAT, ONS1, P.g2_w, P.g2_b);
  k_gpool_out <<<dim3(2),   256, 0, stream>>>(P, OH1, CAT, ONS1, HID);
  k_pairs<<<dim3((E+255)/256,2), 256, 0, stream>>>(P);
  k_Wh2  <<<dim3(N,2),    128, 0, stream>>>(P);
  k_asad2<<<dim3(2),      256, 0, stream>>>(P);
  k_att2 <<<dim3(N,2),    128, 0, stream>>>(P);
  k_e2f  <<<dim3(E,2),    128, 0, stream>>>(P);
  k_xsd2 <<<dim3(2),      256, 0, stream>>>(P);
  k_s2   <<<dim3((E+255)/256,2), 256, 0, stream>>>(P);
  k_ns   <<<dim3(1,2),    256, 0, stream>>>(ODEG2, OSS2, ONS2);
  k_gpool_gate<<<dim3(N,2), 256, 0, stream>>>(P, OH2B, OUTD, ONS2, P.g3_w, P.g3_b);
  k_gpool_out <<<dim3(2),   256, 0, stream>>>(P, OH2B, OUTD, ONS2, HID+CAT);

  // ---- LSTM stack + classifier ----
  k_lstm <<<dim3(2), 512, 0, stream>>>(P, 0);
  k_lstm <<<dim3(2), 512, 0, stream>>>(P, 1);
  k_final<<<dim3(1), 256, 0, stream>>>(P);
}

// Round 5
// 1186.731 us; speedup vs baseline: 2.0574x; 2.0574x over previous
//
#include <hip/hip_runtime.h>
#include <math.h>

#define DI static __device__ __forceinline__

DI float eluf(float x){ return x > 0.f ? x : expm1f(x); }
DI float lreluf(float x){ return x > 0.f ? x : 0.2f*x; }
DI float sigmf(float x){ return 1.f/(1.f+expf(-x)); }

constexpr int N=200, E=3200, HID=64, NH=16, OUTD=128, CAT=2048, SEQD=2240;

// ---- per-graph f32 scratch offsets (in floats) ----
constexpr int OH0   = 0;                 // [N,HID]   elu(feat@W_h)
constexpr int OWH   = OH0 + N*HID;       // [NH,N,OUTD] Wh per head
constexpr int OASN  = OWH + NH*N*OUTD;   // [NH,N]    Wh@a_src
constexpr int OADN  = OASN + NH*N;       // [NH,N]    Wh@a_dst
constexpr int OH1   = OADN + NH*N;       // [N,CAT]   concat head outputs
constexpr int OXW1  = OH1 + N*CAT;       // [N]
constexpr int OXW2  = OXW1 + 256;        // [N]
constexpr int OEW1  = OXW2 + 256;        // [E]
constexpr int OS1   = OEW1 + E;          // [E]
constexpr int ODEG1 = OS1 + E;           // [N]
constexpr int OSS1  = ODEG1 + 256;       // [N]
constexpr int ONS1  = OSS1 + 256;        // [N]
constexpr int OWH2  = ONS1 + 256;        // [N,OUTD]
constexpr int OAS2  = OWH2 + N*OUTD;     // [N]
constexpr int OAD2  = OAS2 + 256;        // [N]
constexpr int OEWV  = OAD2 + 256;        // [E]  RAW e1cat@v_e
constexpr int OH2B  = OEWV + E;          // [N,OUTD]
constexpr int OXS2  = OH2B + N*OUTD;     // [N]
constexpr int OXD2  = OXS2 + 256;        // [N]
constexpr int OEW2  = OXD2 + 256;        // [E]
constexpr int OS2   = OEW2 + E;          // [E]
constexpr int ODEG2 = OS2 + E;           // [N]
constexpr int OSS2  = ODEG2 + 256;       // [N]
constexpr int ONS2  = OSS2 + 256;        // [N]
constexpr int OGATE = ONS2 + 256;        // [N]
constexpr int PGF   = OGATE + 256;       // per-graph float count
// globals: we_ae(1024)@0, v_e(2048)@1024, y0(512)@3072, y1(512)@3584,
//          xseq(4480)@4096, xg(2048)@8576 -> GLOBF=10624
constexpr int GLOBF = 10624;
constexpr int TOTF  = GLOBF + 2*PGF;

// ---- static device scratch: independent of ws_size ----
__device__ float G_F[TOTF];
__device__ int   G_PIDX[2*N*N];

DI float* gf(int g){ return G_F + GLOBF + (size_t)g*PGF; }
DI float* gwe_ae(){ return G_F; }
DI float* gv_e(){ return G_F + 1024; }
DI float* gy0(){ return G_F + 3072; }
DI float* gy1(){ return G_F + 3584; }
DI float* gxseq(){ return G_F + 4096; }
DI float* gxg(){ return G_F + 8576; }     // [t(2)][dir(2)][512]
DI int*   gpidx(int g){ return G_PIDX + g*N*N; }

struct GraphIn {
  const float *feat, *eattr, *adj, *n2n;
  const int   *eidx;
};

struct Params {
  GraphIn g[2];
  const float *W_h, *W_gat, *a_src, *a_dst, *a_e, *We_gat;
  const float *W_out, *ao_src, *ao_dst, *ao_e, *We_out;
  const float *ep1_w, *ep1_b, *ep2_w, *ep2_b;
  const float *g1_w, *g1_b, *g2_w, *g2_b, *g3_w, *g3_b;
  const float *Wih0, *Whh0, *b0, *Wih1, *Whh1, *b1, *fc_w, *fc_b;
  float *out;
};

// ---------------- zero ALL scratch; pairIdx=-1 ----------------
__global__ void k_zero(){
  int idx = blockIdx.x*256 + threadIdx.x;
  if (idx < TOTF) G_F[idx] = 0.f;
  if (idx < 2*N*N) G_PIDX[idx] = -1;
}

// ---------------- precontract We@a_e vectors ----------------
__global__ void k_pre(Params P){
  int idx = blockIdx.x*256 + threadIdx.x;
  if (idx < NH*HID){
    int h = idx/HID, c = idx%HID;
    const float* W = P.We_gat + (size_t)(h*HID + c)*OUTD;
    const float* a = P.a_e + h*OUTD;
    float acc = 0.f;
    for (int o=0;o<OUTD;o++) acc += W[o]*a[o];
    gwe_ae()[idx] = acc;
  } else if (idx < NH*HID + CAT){
    int c = idx - NH*HID;
    const float* W = P.We_out + (size_t)c*OUTD;
    float acc = 0.f;
    for (int o=0;o<OUTD;o++) acc += W[o]*P.ao_e[o];
    gv_e()[c] = acc;
  }
}

// ---------------- h0 = elu(feat @ W_h) ----------------
__global__ void k_h0(Params P){
  int idx = blockIdx.x*256 + threadIdx.x;
  if (idx >= 2*N*HID) return;
  int g = idx/(N*HID), r = idx%(N*HID), n = r/HID, c = r%HID;
  const float* feat = P.g[g].feat;
  float acc = 0.f;
  for (int k=0;k<HID;k++) acc += feat[n*HID+k]*P.W_h[k*HID+c];
  gf(g)[OH0 + n*HID + c] = eluf(acc);
}

// ---------------- Wh[h] = h0 @ W_gat[h] ----------------
__global__ void k_Wh(Params P){
  int n = blockIdx.x, h = blockIdx.y, g = blockIdx.z, o = threadIdx.x;
  __shared__ float hs[HID];
  float* f = gf(g);
  if (o < HID) hs[o] = f[OH0 + n*HID + o];
  __syncthreads();
  const float* W = P.W_gat + (size_t)h*HID*OUTD + o;
  float acc = 0.f;
  for (int c=0;c<HID;c++) acc += hs[c]*W[(size_t)c*OUTD];
  f[OWH + ((size_t)h*N + n)*OUTD + o] = acc;
}

// ---------------- asn/adn = Wh @ a_src / a_dst ----------------
__global__ void k_asad(Params P){
  int h = blockIdx.x, g = blockIdx.y;
  float* f = gf(g);
  for (int n = threadIdx.x; n < N; n += 256){
    const float* wh = f + OWH + ((size_t)h*N + n)*OUTD;
    float s=0.f, d=0.f;
    for (int o=0;o<OUTD;o++){
      float v = wh[o];
      s += v*P.a_src[h*OUTD+o];
      d += v*P.a_dst[h*OUTD+o];
    }
    f[OASN + h*N + n] = s;
    f[OADN + h*N + n] = d;
  }
}

// ---------------- GAT layer 1: row softmax + aggregate (per head) ----------------
__global__ void k_att1(Params P){
  int n = blockIdx.x, h = blockIdx.y, g = blockIdx.z, tid = threadIdx.x;
  __shared__ float z[N];
  __shared__ float red[128];
  float* f = gf(g);
  const float* adj = P.g[g].adj;
  const float* n2n = P.g[g].n2n;
  const float* weae = gwe_ae() + h*HID;
  float asn = f[OASN + h*N + n];
  const float* adn = f + OADN + h*N;
  for (int j = tid; j < N; j += 128){
    float a = adj[n*N + j];
    float zz;
    if (a > 0.f){
      const float* row = n2n + (size_t)(n*N + j)*HID;
      float ee = 0.f;
      for (int c=0;c<HID;c++) ee += row[c]*weae[c];
      zz = lreluf(asn + adn[j] + ee);
    } else zz = -1e9f;
    z[j] = zz;
  }
  __syncthreads();
  float m = -3e38f;
  for (int j = tid; j < N; j += 128) m = fmaxf(m, z[j]);
  red[tid] = m; __syncthreads();
  for (int s=64;s>0;s>>=1){ if (tid<s) red[tid]=fmaxf(red[tid],red[tid+s]); __syncthreads(); }
  m = red[0]; __syncthreads();
  float ssum = 0.f;
  for (int j = tid; j < N; j += 128){ float e = expf(z[j]-m); z[j]=e; ssum += e; }
  red[tid] = ssum; __syncthreads();
  for (int s=64;s>0;s>>=1){ if (tid<s) red[tid]+=red[tid+s]; __syncthreads(); }
  float inv = 1.f/red[0]; __syncthreads();
  const float* wh = f + OWH + (size_t)h*N*OUTD;
  float acc = 0.f;
  for (int j=0;j<N;j++){
    float w = z[j];
    if (w != 0.f) acc += w * wh[(size_t)j*OUTD + tid];
  }
  f[OH1 + (size_t)n*CAT + h*OUTD + tid] = eluf(acc*inv);
}

// ---- fused edge dots: ew1[e], ewv_raw[e]; e1cat recomputed on the fly ----
__global__ void k_edot1(Params P){
  int e = blockIdx.x, g = blockIdx.y, tid = threadIdx.x;   // 128 threads
  __shared__ float es[HID];
  __shared__ float r1[128], r2[128];
  const float* ea = P.g[g].eattr + (size_t)e*HID;
  if (tid < HID) es[tid] = ea[tid];
  __syncthreads();
  float a1 = 0.f, a2 = 0.f;
  for (int h=0; h<NH; ++h){
    const float* W = P.We_gat + (size_t)(h*HID)*OUTD + tid;
    float t = 0.f;
    for (int c=0;c<HID;c++) t += es[c]*W[(size_t)c*OUTD];
    t = eluf(t);
    a1 += t * P.ep1_w[2*CAT + h*OUTD + tid];
    a2 += t * gv_e()[h*OUTD + tid];
  }
  r1[tid]=a1; r2[tid]=a2; __syncthreads();
  for (int s=64;s>0;s>>=1){ if (tid<s){ r1[tid]+=r1[tid+s]; r2[tid]+=r2[tid+s]; } __syncthreads(); }
  if (tid==0){ float* f=gf(g); f[OEW1+e]=r1[0]; f[OEWV+e]=r2[0]; }
}

// ---------------- pool1 node dots ----------------
__global__ void k_xw1(Params P){
  int n = blockIdx.x, wch = blockIdx.y, g = blockIdx.z, tid = threadIdx.x;
  __shared__ float sb[256];
  float* f = gf(g);
  const float* x = f + OH1 + (size_t)n*CAT;
  const float* w = P.ep1_w + wch*CAT;
  float acc = 0.f;
  for (int c = tid; c < CAT; c += 256) acc += x[c]*w[c];
  sb[tid] = acc; __syncthreads();
  for (int s=128;s>0;s>>=1){ if (tid<s) sb[tid]+=sb[tid+s]; __syncthreads(); }
  if (tid==0) f[(wch? OXW2:OXW1) + n] = sb[0];
}

// ---------------- pool1 edge scores + segment sums ----------------
__global__ void k_s1(Params P){
  int e = blockIdx.x*256 + threadIdx.x, g = blockIdx.y;
  if (e >= E) return;
  float* f = gf(g);
  const int* ei = P.g[g].eidx;
  int s = ei[e], d = ei[E+e];
  float v = sigmf(f[OXW1+s] + f[OXW2+d] + f[OEW1+e] + P.ep1_b[0]);
  f[OS1+e] = v;
  atomicAdd(&f[OSS1+s], v);
  atomicAdd(&f[ODEG1+s], 1.f);
}

__global__ void k_ns(int odeg, int oss, int ons){
  int g = blockIdx.y, n = threadIdx.x;
  if (n < N){ float* f = gf(g); f[ons+n] = f[oss+n]/(f[odeg+n]+1e-6f); }
}

// ---------------- pairIdx: last edge wins ----------------
__global__ void k_pairs(Params P){
  int e = blockIdx.x*256 + threadIdx.x, g = blockIdx.y;
  if (e >= E) return;
  const int* ei = P.g[g].eidx;
  atomicMax(&gpidx(g)[ei[e]*N + ei[E+e]], e);
}

// ---------------- global attention pool ----------------
__global__ void k_gpool_gate(Params P, int xoff, int D, int scaleoff, const float* w, const float* b){
  int n = blockIdx.x, g = blockIdx.y, tid = threadIdx.x;
  __shared__ float sb[256];
  float* f = gf(g);
  const float* x = f + xoff + (size_t)n*D;
  float acc = 0.f;
  for (int c = tid; c < D; c += 256) acc += x[c]*w[c];
  sb[tid] = acc; __syncthreads();
  for (int s=128;s>0;s>>=1){ if (tid<s) sb[tid]+=sb[tid+s]; __syncthreads(); }
  if (tid==0){
    float sc = scaleoff>=0 ? f[scaleoff+n] : 1.f;
    f[OGATE+n] = sigmf(sb[0]*sc + b[0]);
  }
}

__global__ void k_gpool_out(Params P, int xoff, int D, int scaleoff, int outoff){
  int g = blockIdx.x, tid = threadIdx.x;
  __shared__ float att[N];
  __shared__ float sb[256];
  float* f = gf(g);
  float m = -3e38f;
  for (int n = tid; n < N; n += 256) m = fmaxf(m, f[OGATE+n]);
  sb[tid] = m; __syncthreads();
  for (int s=128;s>0;s>>=1){ if (tid<s) sb[tid]=fmaxf(sb[tid],sb[tid+s]); __syncthreads(); }
  m = sb[0]; __syncthreads();
  float ss = 0.f;
  for (int n = tid; n < N; n += 256){ float e = expf(f[OGATE+n]-m); att[n]=e; ss += e; }
  sb[tid] = ss; __syncthreads();
  for (int s=128;s>0;s>>=1){ if (tid<s) sb[tid]+=sb[tid+s]; __syncthreads(); }
  float inv = 1.f/sb[0]; __syncthreads();
  for (int n = tid; n < N; n += 256){
    float sc = scaleoff>=0 ? f[scaleoff+n] : 1.f;
    att[n] *= inv*sc;
  }
  __syncthreads();
  const float* x = f + xoff;
  for (int c = tid; c < D; c += 256){
    float acc = 0.f;
    for (int n=0;n<N;n++) acc += att[n]*x[(size_t)n*D + c];
    gxseq()[g*SEQD + outoff + c] = acc;
  }
}

// ---------------- Wh2 = (h1cat @ W_out) * ns1 ----------------
__global__ void k_Wh2(Params P){
  int n = blockIdx.x, g = blockIdx.y, tid = threadIdx.x;
  __shared__ float hrow[128];
  float* f = gf(g);
  const float* x = f + OH1 + (size_t)n*CAT;
  float ns = f[ONS1+n];
  float acc = 0.f;
  for (int c0=0;c0<CAT;c0+=128){
    __syncthreads();
    hrow[tid] = x[c0+tid];
    __syncthreads();
    const float* W = P.W_out + (size_t)c0*OUTD + tid;
    for (int cc=0;cc<128;cc++) acc += hrow[cc]*W[(size_t)cc*OUTD];
  }
  f[OWH2 + (size_t)n*OUTD + tid] = acc*ns;
}

__global__ void k_asad2(Params P){
  int g = blockIdx.x;
  float* f = gf(g);
  for (int n = threadIdx.x; n < N; n += 256){
    const float* wh = f + OWH2 + (size_t)n*OUTD;
    float s=0.f, d=0.f;
    for (int o=0;o<OUTD;o++){
      float v = wh[o];
      s += v*P.ao_src[o];
      d += v*P.ao_dst[o];
    }
    f[OAS2+n]=s; f[OAD2+n]=d;
  }
}

// ---------------- GAT layer 2 ----------------
__global__ void k_att2(Params P){
  int n = blockIdx.x, g = blockIdx.y, tid = threadIdx.x;
  __shared__ float z[N];
  __shared__ float red[128];
  float* f = gf(g);
  const float* adj = P.g[g].adj;
  const int* pidx = gpidx(g);
  float asn = f[OAS2+n];
  const float* adn = f + OAD2;
  for (int j = tid; j < N; j += 128){
    float a = adj[n*N + j];
    float zz;
    if (a > 0.f){
      int p = pidx[n*N + j];
      float ee = (p >= 0) ? f[OEWV+p]*f[OS1+p] : 0.f;
      zz = lreluf(asn + adn[j] + ee);
    } else zz = -1e9f;
    z[j] = zz;
  }
  __syncthreads();
  float m = -3e38f;
  for (int j = tid; j < N; j += 128) m = fmaxf(m, z[j]);
  red[tid] = m; __syncthreads();
  for (int s=64;s>0;s>>=1){ if (tid<s) red[tid]=fmaxf(red[tid],red[tid+s]); __syncthreads(); }
  m = red[0]; __syncthreads();
  float ssum = 0.f;
  for (int j = tid; j < N; j += 128){ float e = expf(z[j]-m); z[j]=e; ssum += e; }
  red[tid] = ssum; __syncthreads();
  for (int s=64;s>0;s>>=1){ if (tid<s) red[tid]+=red[tid+s]; __syncthreads(); }
  float inv = 1.f/red[0]; __syncthreads();
  const float* wh = f + OWH2;
  float acc = 0.f;
  for (int j=0;j<N;j++){
    float w = z[j];
    if (w != 0.f) acc += w * wh[(size_t)j*OUTD + tid];
  }
  f[OH2B + (size_t)n*OUTD + tid] = acc*inv;   // concat=False: no elu
}

// ---- fused e2 + ew2 ----
__global__ void k_e2f(Params P){
  int e = blockIdx.x, g = blockIdx.y, tid = threadIdx.x;   // 128 threads
  __shared__ float es[HID];
  __shared__ float tcol[128];
  __shared__ float red[128];
  float* f = gf(g);
  const float* ea = P.g[g].eattr + (size_t)e*HID;
  if (tid < HID) es[tid] = ea[tid];
  __syncthreads();
  float acc = 0.f;
  for (int h=0; h<NH; ++h){
    const float* W1 = P.We_gat + (size_t)(h*HID)*OUTD + tid;
    float t = 0.f;
    for (int c=0;c<HID;c++) t += es[c]*W1[(size_t)c*OUTD];
    t = eluf(t);
    __syncthreads();
    tcol[tid] = t;
    __syncthreads();
    const float* W2 = P.We_out + (size_t)(h*OUTD)*OUTD + tid;
    for (int o=0;o<OUTD;o++) acc += tcol[o]*W2[(size_t)o*OUTD];
  }
  float v = eluf(f[OS1+e]*acc);
  red[tid] = v * P.ep2_w[2*OUTD + tid];
  __syncthreads();
  for (int s=64;s>0;s>>=1){ if (tid<s) red[tid]+=red[tid+s]; __syncthreads(); }
  if (tid==0) f[OEW2+e] = red[0];
}

// ---------------- pool2 node dots ----------------
__global__ void k_xsd2(Params P){
  int g = blockIdx.x;
  float* f = gf(g);
  for (int n = threadIdx.x; n < N; n += 256){
    const float* x = f + OH2B + (size_t)n*OUTD;
    float s=0.f, d=0.f;
    for (int k=0;k<OUTD;k++){
      float v = x[k];
      s += v*P.ep2_w[k];
      d += v*P.ep2_w[OUTD+k];
    }
    f[OXS2+n]=s; f[OXD2+n]=d;
  }
}

__global__ void k_s2(Params P){
  int e = blockIdx.x*256 + threadIdx.x, g = blockIdx.y;
  if (e >= E) return;
  float* f = gf(g);
  const int* ei = P.g[g].eidx;
  int s = ei[e], d = ei[E+e];
  float v = sigmf(f[OXS2+s] + f[OXD2+d] + f[OEW2+e] + P.ep2_b[0]);
  f[OS2+e] = v;
  atomicAdd(&f[OSS2+s], v);
  atomicAdd(&f[ODEG2+s], 1.f);
}

// ---- LSTM input projection: xg[t][d][512] = b + x[t] @ Wih[d]^T ----
// one wave per gate row; lane-coalesced over Din; shuffle reduce
__global__ void k_lstm_xg(Params P, int layer){
  int gid = blockIdx.x*4 + (threadIdx.x>>6);   // gate id in [0, 2*2*512)
  int lane = threadIdx.x & 63;
  int t = gid >> 10;
  int rem = gid & 1023;
  int d = rem >> 9;
  int gate = rem & 511;
  const float* Wih = layer ? P.Wih1 : P.Wih0;
  const float* bb  = layer ? P.b1   : P.b0;
  const float* xin = layer ? gy0()  : gxseq();
  int Din = layer ? 256 : SEQD;
  const float* x = xin + t*Din;
  const float* Wr = Wih + ((size_t)d*512 + gate)*Din;
  float acc = 0.f;
  for (int k=lane; k<Din; k+=64) acc += x[k]*Wr[k];
  for (int off=32; off>0; off>>=1) acc += __shfl_down(acc, off);
  if (lane==0) gxg()[(t*2 + d)*512 + gate] = acc + bb[d*512 + gate];
}

// ---- LSTM recurrence only: gates = xg + h @ Whh^T; cell update ----
__global__ void k_lstm_rec(Params P, int layer){
  int d = blockIdx.x, tid = threadIdx.x;      // 512 threads, 1 block per dir
  const float* Whh = layer ? P.Whh1 : P.Whh0;
  float* yout = layer ? gy1() : gy0();
  __shared__ float h[128], c[128], gbuf[512];
  if (tid < 128){ h[tid]=0.f; c[tid]=0.f; }
  __syncthreads();
  for (int s=0;s<2;s++){
    int t = (d==0) ? s : 1-s;
    float acc = gxg()[(t*2 + d)*512 + tid];
    const float* Ur = Whh + ((size_t)d*512 + tid)*128;
    for (int k=0;k<128;k++) acc += h[k]*Ur[k];
    gbuf[tid] = acc;
    __syncthreads();
    if (tid < 128){
      float ii = sigmf(gbuf[tid]);
      float ff = sigmf(gbuf[128+tid]);
      float gg = tanhf(gbuf[256+tid]);
      float oo = sigmf(gbuf[384+tid]);
      float cn = ff*c[tid] + ii*gg;
      c[tid] = cn;
      float hn = oo*tanhf(cn);
      h[tid] = hn;
      yout[t*256 + d*128 + tid] = hn;
    }
    __syncthreads();
  }
}

// ---------------- final FC + softmax ----------------
__global__ void k_final(Params P){
  int tid = threadIdx.x;
  __shared__ float sb[256], sb2[256];
  const float* x = gy1() + 256;  // x[-1]
  sb[tid]  = x[tid]*P.fc_w[tid*2+0];
  sb2[tid] = x[tid]*P.fc_w[tid*2+1];
  __syncthreads();
  for (int s=128;s>0;s>>=1){ if (tid<s){ sb[tid]+=sb[tid+s]; sb2[tid]+=sb2[tid+s]; } __syncthreads(); }
  if (tid==0){
    float l0 = sb[0] + P.fc_b[0];
    float l1 = sb2[0] + P.fc_b[1];
    float m = fmaxf(l0,l1);
    float e0 = expf(l0-m), e1 = expf(l1-m), inv = 1.f/(e0+e1);
    P.out[0] = e0*inv;
    P.out[1] = e1*inv;
  }
}

extern "C" void kernel_launch(void* const* d_in, const int* in_sizes, int n_in,
                              void* d_out, int out_size, void* d_ws, size_t ws_size,
                              hipStream_t stream){
  Params P;
  for (int g=0; g<2; ++g){
    int b = g*5;
    P.g[g].feat  = (const float*)d_in[b+0];
    P.g[g].eidx  = (const int*)d_in[b+1];
    P.g[g].eattr = (const float*)d_in[b+2];
    P.g[g].adj   = (const float*)d_in[b+3];
    P.g[g].n2n   = (const float*)d_in[b+4];
  }
  P.W_h   = (const float*)d_in[10];
  P.W_gat = (const float*)d_in[11];
  P.a_src = (const float*)d_in[12];
  P.a_dst = (const float*)d_in[13];
  P.a_e   = (const float*)d_in[14];
  P.We_gat= (const float*)d_in[15];
  P.W_out = (const float*)d_in[16];
  P.ao_src= (const float*)d_in[17];
  P.ao_dst= (const float*)d_in[18];
  P.ao_e  = (const float*)d_in[19];
  P.We_out= (const float*)d_in[20];
  P.ep1_w = (const float*)d_in[21];
  P.ep1_b = (const float*)d_in[22];
  P.ep2_w = (const float*)d_in[23];
  P.ep2_b = (const float*)d_in[24];
  P.g1_w  = (const float*)d_in[25];
  P.g1_b  = (const float*)d_in[26];
  P.g2_w  = (const float*)d_in[27];
  P.g2_b  = (const float*)d_in[28];
  P.g3_w  = (const float*)d_in[29];
  P.g3_b  = (const float*)d_in[30];
  P.Wih0  = (const float*)d_in[31];
  P.Whh0  = (const float*)d_in[32];
  P.b0    = (const float*)d_in[33];
  P.Wih1  = (const float*)d_in[34];
  P.Whh1  = (const float*)d_in[35];
  P.b1    = (const float*)d_in[36];
  P.fc_w  = (const float*)d_in[37];
  P.fc_b  = (const float*)d_in[38];
  P.out   = (float*)d_out;

  // ---- graph stages (both graphs in each kernel via grid dim) ----
  k_zero <<<dim3((TOTF+255)/256 + 1), 256, 0, stream>>>();
  k_pre  <<<dim3((NH*HID+CAT+255)/256), 256, 0, stream>>>(P);
  k_h0   <<<dim3((2*N*HID+255)/256), 256, 0, stream>>>(P);
  k_gpool_gate<<<dim3(N,2), 256, 0, stream>>>(P, OH0, HID, -1, P.g1_w, P.g1_b);
  k_gpool_out <<<dim3(2),   256, 0, stream>>>(P, OH0, HID, -1, 0);
  k_Wh   <<<dim3(N,NH,2), 128, 0, stream>>>(P);
  k_asad <<<dim3(NH,2),   256, 0, stream>>>(P);
  k_att1 <<<dim3(N,NH,2), 128, 0, stream>>>(P);
  k_edot1<<<dim3(E,2),    128, 0, stream>>>(P);
  k_xw1  <<<dim3(N,2,2),  256, 0, stream>>>(P);
  k_s1   <<<dim3((E+255)/256,2), 256, 0, stream>>>(P);
  k_ns   <<<dim3(1,2),    256, 0, stream>>>(ODEG1, OSS1, ONS1);
  k_gpool_gate<<<dim3(N,2), 256, 0, stream>>>(P, OH1, CAT, ONS1, P.g2_w, P.g2_b);
  k_gpool_out <<<dim3(2),   256, 0, stream>>>(P, OH1, CAT, ONS1, HID);
  k_pairs<<<dim3((E+255)/256,2), 256, 0, stream>>>(P);
  k_Wh2  <<<dim3(N,2),    128, 0, stream>>>(P);
  k_asad2<<<dim3(2),      256, 0, stream>>>(P);
  k_att2 <<<dim3(N,2),    128, 0, stream>>>(P);
  k_e2f  <<<dim3(E,2),    128, 0, stream>>>(P);
  k_xsd2 <<<dim3(2),      256, 0, stream>>>(P);
  k_s2   <<<dim3((E+255)/256,2), 256, 0, stream>>>(P);
  k_ns   <<<dim3(1,2),    256, 0, stream>>>(ODEG2, OSS2, ONS2);
  k_gpool_gate<<<dim3(N,2), 256, 0, stream>>>(P, OH2B, OUTD, ONS2, P.g3_w, P.g3_b);
  k_gpool_out <<<dim3(2),   256, 0, stream>>>(P, OH2B, OUTD, ONS2, HID+CAT);

  // ---- LSTM stack + classifier ----
  k_lstm_xg <<<dim3(512), 256, 0, stream>>>(P, 0);   // 2048 gates / 4 per block
  k_lstm_rec<<<dim3(2),   512, 0, stream>>>(P, 0);
  k_lstm_xg <<<dim3(512), 256, 0, stream>>>(P, 1);
  k_lstm_rec<<<dim3(2),   512, 0, stream>>>(P, 1);
  k_final<<<dim3(1), 256, 0, stream>>>(P);
}

// Round 6
// 953.770 us; speedup vs baseline: 2.5599x; 1.2443x over previous
//
#include <hip/hip_runtime.h>
#include <math.h>

#define DI static __device__ __forceinline__

DI float eluf(float x){ return x > 0.f ? x : expm1f(x); }
DI float lreluf(float x){ return x > 0.f ? x : 0.2f*x; }
DI float sigmf(float x){ return 1.f/(1.f+expf(-x)); }

constexpr int N=200, E=3200, HID=64, NH=16, OUTD=128, CAT=2048, SEQD=2240;

// ---- per-graph f32 scratch offsets (in floats) ----
constexpr int OH0   = 0;                 // [N,HID]   elu(feat@W_h)
constexpr int OWH   = OH0 + N*HID;       // [NH,N,OUTD] Wh per head
constexpr int OASN  = OWH + NH*N*OUTD;   // [NH,N]    Wh@a_src
constexpr int OADN  = OASN + NH*N;       // [NH,N]    Wh@a_dst
constexpr int OH1   = OADN + NH*N;       // [N,CAT]   concat head outputs
constexpr int OXW1  = OH1 + N*CAT;       // [N]
constexpr int OXW2  = OXW1 + 256;        // [N]
constexpr int OEW1  = OXW2 + 256;        // [E]
constexpr int OS1   = OEW1 + E;          // [E]
constexpr int ODEG1 = OS1 + E;           // [N]
constexpr int OSS1  = ODEG1 + 256;       // [N]
constexpr int ONS1  = OSS1 + 256;        // [N]
constexpr int OWH2  = ONS1 + 256;        // [N,OUTD]
constexpr int OAS2  = OWH2 + N*OUTD;     // [N]
constexpr int OAD2  = OAS2 + 256;        // [N]
constexpr int OEWV  = OAD2 + 256;        // [E]  RAW e1cat@v_e
constexpr int OH2B  = OEWV + E;          // [N,OUTD]
constexpr int OXS2  = OH2B + N*OUTD;     // [N]
constexpr int OXD2  = OXS2 + 256;        // [N]
constexpr int OEW2  = OXD2 + 256;        // [E]
constexpr int OS2   = OEW2 + E;          // [E]
constexpr int ODEG2 = OS2 + E;           // [N]
constexpr int OSS2  = ODEG2 + 256;       // [N]
constexpr int ONS2  = OSS2 + 256;        // [N]
constexpr int OGATE = ONS2 + 256;        // [N]
constexpr int PGF   = OGATE + 256;       // per-graph float count
constexpr int GLOBF = 10624;
constexpr int TOTF  = GLOBF + 2*PGF;

// ---- static device scratch: independent of ws_size ----
__device__ float G_F[TOTF];
__device__ int   G_PIDX[2*N*N];

DI float* gf(int g){ return G_F + GLOBF + (size_t)g*PGF; }
DI float* gwe_ae(){ return G_F; }
DI float* gv_e(){ return G_F + 1024; }
DI float* gy0(){ return G_F + 3072; }
DI float* gy1(){ return G_F + 3584; }
DI float* gxseq(){ return G_F + 4096; }
DI float* gxg(){ return G_F + 8576; }     // [t(2)][dir(2)][512]
DI int*   gpidx(int g){ return G_PIDX + g*N*N; }

struct GraphIn {
  const float *feat, *eattr, *adj, *n2n;
  const int   *eidx;
};

struct Params {
  GraphIn g[2];
  const float *W_h, *W_gat, *a_src, *a_dst, *a_e, *We_gat;
  const float *W_out, *ao_src, *ao_dst, *ao_e, *We_out;
  const float *ep1_w, *ep1_b, *ep2_w, *ep2_b;
  const float *g1_w, *g1_b, *g2_w, *g2_b, *g3_w, *g3_b;
  const float *Wih0, *Whh0, *b0, *Wih1, *Whh1, *b1, *fc_w, *fc_b;
  float *out;
};

// ---------------- zero ALL scratch; pairIdx=-1 ----------------
__global__ void k_zero(){
  int idx = blockIdx.x*256 + threadIdx.x;
  if (idx < TOTF) G_F[idx] = 0.f;
  if (idx < 2*N*N) G_PIDX[idx] = -1;
}

// ---------------- precontract We@a_e vectors ----------------
__global__ void k_pre(Params P){
  int idx = blockIdx.x*256 + threadIdx.x;
  if (idx < NH*HID){
    int h = idx/HID, c = idx%HID;
    const float* W = P.We_gat + (size_t)(h*HID + c)*OUTD;
    const float* a = P.a_e + h*OUTD;
    float acc = 0.f;
    for (int o=0;o<OUTD;o++) acc += W[o]*a[o];
    gwe_ae()[idx] = acc;
  } else if (idx < NH*HID + CAT){
    int c = idx - NH*HID;
    const float* W = P.We_out + (size_t)c*OUTD;
    float acc = 0.f;
    for (int o=0;o<OUTD;o++) acc += W[o]*P.ao_e[o];
    gv_e()[c] = acc;
  }
}

// ---------------- h0 = elu(feat @ W_h) ----------------
__global__ void k_h0(Params P){
  int idx = blockIdx.x*256 + threadIdx.x;
  if (idx >= 2*N*HID) return;
  int g = idx/(N*HID), r = idx%(N*HID), n = r/HID, c = r%HID;
  const float* feat = P.g[g].feat;
  float acc = 0.f;
  for (int k=0;k<HID;k++) acc += feat[n*HID+k]*P.W_h[k*HID+c];
  gf(g)[OH0 + n*HID + c] = eluf(acc);
}

// ---------------- Wh[h] = h0 @ W_gat[h] ----------------
__global__ void k_Wh(Params P){
  int n = blockIdx.x, h = blockIdx.y, g = blockIdx.z, o = threadIdx.x;
  __shared__ float hs[HID];
  float* f = gf(g);
  if (o < HID) hs[o] = f[OH0 + n*HID + o];
  __syncthreads();
  const float* W = P.W_gat + (size_t)h*HID*OUTD + o;
  float acc = 0.f;
  for (int c=0;c<HID;c++) acc += hs[c]*W[(size_t)c*OUTD];
  f[OWH + ((size_t)h*N + n)*OUTD + o] = acc;
}

// ---------------- asn/adn = Wh @ a_src / a_dst ----------------
__global__ void k_asad(Params P){
  int h = blockIdx.x, g = blockIdx.y;
  float* f = gf(g);
  for (int n = threadIdx.x; n < N; n += 256){
    const float* wh = f + OWH + ((size_t)h*N + n)*OUTD;
    float s=0.f, d=0.f;
    for (int o=0;o<OUTD;o++){
      float v = wh[o];
      s += v*P.a_src[h*OUTD+o];
      d += v*P.a_dst[h*OUTD+o];
    }
    f[OASN + h*N + n] = s;
    f[OADN + h*N + n] = d;
  }
}

// ---------------- GAT layer 1: row softmax + aggregate (per head) ----------------
__global__ void k_att1(Params P){
  int n = blockIdx.x, h = blockIdx.y, g = blockIdx.z, tid = threadIdx.x;
  __shared__ float z[N];
  __shared__ float red[128];
  float* f = gf(g);
  const float* adj = P.g[g].adj;
  const float* n2n = P.g[g].n2n;
  const float* weae = gwe_ae() + h*HID;
  float asn = f[OASN + h*N + n];
  const float* adn = f + OADN + h*N;
  for (int j = tid; j < N; j += 128){
    float a = adj[n*N + j];
    float zz;
    if (a > 0.f){
      const float* row = n2n + (size_t)(n*N + j)*HID;
      float ee = 0.f;
      for (int c=0;c<HID;c++) ee += row[c]*weae[c];
      zz = lreluf(asn + adn[j] + ee);
    } else zz = -1e9f;
    z[j] = zz;
  }
  __syncthreads();
  float m = -3e38f;
  for (int j = tid; j < N; j += 128) m = fmaxf(m, z[j]);
  red[tid] = m; __syncthreads();
  for (int s=64;s>0;s>>=1){ if (tid<s) red[tid]=fmaxf(red[tid],red[tid+s]); __syncthreads(); }
  m = red[0]; __syncthreads();
  float ssum = 0.f;
  for (int j = tid; j < N; j += 128){ float e = expf(z[j]-m); z[j]=e; ssum += e; }
  red[tid] = ssum; __syncthreads();
  for (int s=64;s>0;s>>=1){ if (tid<s) red[tid]+=red[tid+s]; __syncthreads(); }
  float inv = 1.f/red[0]; __syncthreads();
  const float* wh = f + OWH + (size_t)h*N*OUTD;
  float acc = 0.f;
  for (int j=0;j<N;j++){
    float w = z[j];
    if (w != 0.f) acc += w * wh[(size_t)j*OUTD + tid];
  }
  f[OH1 + (size_t)n*CAT + h*OUTD + tid] = eluf(acc*inv);
}

// ---- fused edge dots, 8 edges/block: ew1[e], ewv_raw[e] ----
constexpr int TE1 = 8;
__global__ void k_edot1(Params P){
  int e0 = blockIdx.x*TE1, g = blockIdx.y, tid = threadIdx.x;   // 128 threads
  __shared__ float es[TE1][HID];
  __shared__ float lred[2][TE1][2];
  const float* ea = P.g[g].eattr + (size_t)e0*HID;
  for (int i = tid; i < TE1*HID; i += 128) ((float*)es)[i] = ea[i];
  __syncthreads();
  float a1[TE1], a2[TE1];
  for (int e=0;e<TE1;e++){ a1[e]=0.f; a2[e]=0.f; }
  for (int h=0; h<NH; ++h){
    const float* W = P.We_gat + (size_t)(h*HID)*OUTD + tid;
    float t[TE1];
    for (int e=0;e<TE1;e++) t[e]=0.f;
    for (int c=0;c<HID;c++){
      float w = W[(size_t)c*OUTD];
      for (int e=0;e<TE1;e++) t[e] += es[e][c]*w;
    }
    float w1 = P.ep1_w[2*CAT + h*OUTD + tid];
    float wv = gv_e()[h*OUTD + tid];
    for (int e=0;e<TE1;e++){
      float u = eluf(t[e]);
      a1[e] += u*w1;
      a2[e] += u*wv;
    }
  }
  int lane = tid & 63, wvi = tid >> 6;
  for (int e=0;e<TE1;e++){
    float v1=a1[e], v2=a2[e];
    for (int off=32;off>0;off>>=1){ v1 += __shfl_down(v1,off); v2 += __shfl_down(v2,off); }
    if (lane==0){ lred[wvi][e][0]=v1; lred[wvi][e][1]=v2; }
  }
  __syncthreads();
  if (tid < TE1*2){
    int e = tid>>1, which = tid&1;
    float s = lred[0][e][which]+lred[1][e][which];
    gf(g)[(which? OEWV:OEW1) + e0+e] = s;
  }
}

// ---------------- pool1 node dots ----------------
__global__ void k_xw1(Params P){
  int n = blockIdx.x, wch = blockIdx.y, g = blockIdx.z, tid = threadIdx.x;
  __shared__ float sb[256];
  float* f = gf(g);
  const float* x = f + OH1 + (size_t)n*CAT;
  const float* w = P.ep1_w + wch*CAT;
  float acc = 0.f;
  for (int c = tid; c < CAT; c += 256) acc += x[c]*w[c];
  sb[tid] = acc; __syncthreads();
  for (int s=128;s>0;s>>=1){ if (tid<s) sb[tid]+=sb[tid+s]; __syncthreads(); }
  if (tid==0) f[(wch? OXW2:OXW1) + n] = sb[0];
}

// ---------------- pool1 edge scores + segment sums ----------------
__global__ void k_s1(Params P){
  int e = blockIdx.x*256 + threadIdx.x, g = blockIdx.y;
  if (e >= E) return;
  float* f = gf(g);
  const int* ei = P.g[g].eidx;
  int s = ei[e], d = ei[E+e];
  float v = sigmf(f[OXW1+s] + f[OXW2+d] + f[OEW1+e] + P.ep1_b[0]);
  f[OS1+e] = v;
  atomicAdd(&f[OSS1+s], v);
  atomicAdd(&f[ODEG1+s], 1.f);
}

__global__ void k_ns(int odeg, int oss, int ons){
  int g = blockIdx.y, n = threadIdx.x;
  if (n < N){ float* f = gf(g); f[ons+n] = f[oss+n]/(f[odeg+n]+1e-6f); }
}

// ---------------- pairIdx: last edge wins ----------------
__global__ void k_pairs(Params P){
  int e = blockIdx.x*256 + threadIdx.x, g = blockIdx.y;
  if (e >= E) return;
  const int* ei = P.g[g].eidx;
  atomicMax(&gpidx(g)[ei[e]*N + ei[E+e]], e);
}

// ---------------- global attention pool ----------------
__global__ void k_gpool_gate(Params P, int xoff, int D, int scaleoff, const float* w, const float* b){
  int n = blockIdx.x, g = blockIdx.y, tid = threadIdx.x;
  __shared__ float sb[256];
  float* f = gf(g);
  const float* x = f + xoff + (size_t)n*D;
  float acc = 0.f;
  for (int c = tid; c < D; c += 256) acc += x[c]*w[c];
  sb[tid] = acc; __syncthreads();
  for (int s=128;s>0;s>>=1){ if (tid<s) sb[tid]+=sb[tid+s]; __syncthreads(); }
  if (tid==0){
    float sc = scaleoff>=0 ? f[scaleoff+n] : 1.f;
    f[OGATE+n] = sigmf(sb[0]*sc + b[0]);
  }
}

__global__ void k_gpool_out(Params P, int xoff, int D, int scaleoff, int outoff){
  int g = blockIdx.x, tid = threadIdx.x;
  __shared__ float att[N];
  __shared__ float sb[256];
  float* f = gf(g);
  float m = -3e38f;
  for (int n = tid; n < N; n += 256) m = fmaxf(m, f[OGATE+n]);
  sb[tid] = m; __syncthreads();
  for (int s=128;s>0;s>>=1){ if (tid<s) sb[tid]=fmaxf(sb[tid],sb[tid+s]); __syncthreads(); }
  m = sb[0]; __syncthreads();
  float ss = 0.f;
  for (int n = tid; n < N; n += 256){ float e = expf(f[OGATE+n]-m); att[n]=e; ss += e; }
  sb[tid] = ss; __syncthreads();
  for (int s=128;s>0;s>>=1){ if (tid<s) sb[tid]+=sb[tid+s]; __syncthreads(); }
  float inv = 1.f/sb[0]; __syncthreads();
  for (int n = tid; n < N; n += 256){
    float sc = scaleoff>=0 ? f[scaleoff+n] : 1.f;
    att[n] *= inv*sc;
  }
  __syncthreads();
  const float* x = f + xoff;
  for (int c = tid; c < D; c += 256){
    float acc = 0.f;
    for (int n=0;n<N;n++) acc += att[n]*x[(size_t)n*D + c];
    gxseq()[g*SEQD + outoff + c] = acc;
  }
}

// ---------------- Wh2 = (h1cat @ W_out) * ns1 ----------------
__global__ void k_Wh2(Params P){
  int n = blockIdx.x, g = blockIdx.y, tid = threadIdx.x;
  __shared__ float hrow[128];
  float* f = gf(g);
  const float* x = f + OH1 + (size_t)n*CAT;
  float ns = f[ONS1+n];
  float acc = 0.f;
  for (int c0=0;c0<CAT;c0+=128){
    __syncthreads();
    hrow[tid] = x[c0+tid];
    __syncthreads();
    const float* W = P.W_out + (size_t)c0*OUTD + tid;
    for (int cc=0;cc<128;cc++) acc += hrow[cc]*W[(size_t)cc*OUTD];
  }
  f[OWH2 + (size_t)n*OUTD + tid] = acc*ns;
}

__global__ void k_asad2(Params P){
  int g = blockIdx.x;
  float* f = gf(g);
  for (int n = threadIdx.x; n < N; n += 256){
    const float* wh = f + OWH2 + (size_t)n*OUTD;
    float s=0.f, d=0.f;
    for (int o=0;o<OUTD;o++){
      float v = wh[o];
      s += v*P.ao_src[o];
      d += v*P.ao_dst[o];
    }
    f[OAS2+n]=s; f[OAD2+n]=d;
  }
}

// ---------------- GAT layer 2 ----------------
__global__ void k_att2(Params P){
  int n = blockIdx.x, g = blockIdx.y, tid = threadIdx.x;
  __shared__ float z[N];
  __shared__ float red[128];
  float* f = gf(g);
  const float* adj = P.g[g].adj;
  const int* pidx = gpidx(g);
  float asn = f[OAS2+n];
  const float* adn = f + OAD2;
  for (int j = tid; j < N; j += 128){
    float a = adj[n*N + j];
    float zz;
    if (a > 0.f){
      int p = pidx[n*N + j];
      float ee = (p >= 0) ? f[OEWV+p]*f[OS1+p] : 0.f;
      zz = lreluf(asn + adn[j] + ee);
    } else zz = -1e9f;
    z[j] = zz;
  }
  __syncthreads();
  float m = -3e38f;
  for (int j = tid; j < N; j += 128) m = fmaxf(m, z[j]);
  red[tid] = m; __syncthreads();
  for (int s=64;s>0;s>>=1){ if (tid<s) red[tid]=fmaxf(red[tid],red[tid+s]); __syncthreads(); }
  m = red[0]; __syncthreads();
  float ssum = 0.f;
  for (int j = tid; j < N; j += 128){ float e = expf(z[j]-m); z[j]=e; ssum += e; }
  red[tid] = ssum; __syncthreads();
  for (int s=64;s>0;s>>=1){ if (tid<s) red[tid]+=red[tid+s]; __syncthreads(); }
  float inv = 1.f/red[0]; __syncthreads();
  const float* wh = f + OWH2;
  float acc = 0.f;
  for (int j=0;j<N;j++){
    float w = z[j];
    if (w != 0.f) acc += w * wh[(size_t)j*OUTD + tid];
  }
  f[OH2B + (size_t)n*OUTD + tid] = acc*inv;   // concat=False: no elu
}

// ---- fused e2 + ew2, 16 edges/block ----
constexpr int TE2 = 16;
__global__ void k_e2f(Params P){
  int e0 = blockIdx.x*TE2, g = blockIdx.y, tid = threadIdx.x;   // 128 threads
  __shared__ float es[TE2][HID];       // 4KB
  __shared__ float tcol[TE2][OUTD];    // 8KB
  __shared__ float lred[2][TE2];
  float* f = gf(g);
  const float* ea = P.g[g].eattr + (size_t)e0*HID;
  for (int i = tid; i < TE2*HID; i += 128) ((float*)es)[i] = ea[i];
  __syncthreads();
  float acc[TE2];
  for (int e=0;e<TE2;e++) acc[e]=0.f;
  for (int h=0; h<NH; ++h){
    const float* W1 = P.We_gat + (size_t)(h*HID)*OUTD + tid;
    float t[TE2];
    for (int e=0;e<TE2;e++) t[e]=0.f;
    for (int c=0;c<HID;c++){
      float w = W1[(size_t)c*OUTD];
      for (int e=0;e<TE2;e++) t[e] += es[e][c]*w;
    }
    __syncthreads();                 // previous tcol fully consumed
    for (int e=0;e<TE2;e++) tcol[e][tid] = eluf(t[e]);
    __syncthreads();
    const float* W2 = P.We_out + (size_t)(h*OUTD)*OUTD + tid;
    for (int o=0;o<OUTD;o++){
      float w = W2[(size_t)o*OUTD];
      for (int e=0;e<TE2;e++) acc[e] += tcol[e][o]*w;
    }
  }
  float w2 = P.ep2_w[2*OUTD + tid];
  int lane = tid & 63, wvi = tid >> 6;
  for (int e=0;e<TE2;e++){
    float v = eluf(f[OS1+e0+e]*acc[e]) * w2;
    for (int off=32;off>0;off>>=1) v += __shfl_down(v,off);
    if (lane==0) lred[wvi][e]=v;
  }
  __syncthreads();
  if (tid < TE2) f[OEW2+e0+tid] = lred[0][tid]+lred[1][tid];
}

// ---------------- pool2 node dots ----------------
__global__ void k_xsd2(Params P){
  int g = blockIdx.x;
  float* f = gf(g);
  for (int n = threadIdx.x; n < N; n += 256){
    const float* x = f + OH2B + (size_t)n*OUTD;
    float s=0.f, d=0.f;
    for (int k=0;k<OUTD;k++){
      float v = x[k];
      s += v*P.ep2_w[k];
      d += v*P.ep2_w[OUTD+k];
    }
    f[OXS2+n]=s; f[OXD2+n]=d;
  }
}

__global__ void k_s2(Params P){
  int e = blockIdx.x*256 + threadIdx.x, g = blockIdx.y;
  if (e >= E) return;
  float* f = gf(g);
  const int* ei = P.g[g].eidx;
  int s = ei[e], d = ei[E+e];
  float v = sigmf(f[OXS2+s] + f[OXD2+d] + f[OEW2+e] + P.ep2_b[0]);
  f[OS2+e] = v;
  atomicAdd(&f[OSS2+s], v);
  atomicAdd(&f[ODEG2+s], 1.f);
}

// ---- LSTM input projection: xg[t][d][512] = b + x[t] @ Wih[d]^T ----
__global__ void k_lstm_xg(Params P, int layer){
  int gid = blockIdx.x*4 + (threadIdx.x>>6);
  int lane = threadIdx.x & 63;
  int t = gid >> 10;
  int rem = gid & 1023;
  int d = rem >> 9;
  int gate = rem & 511;
  const float* Wih = layer ? P.Wih1 : P.Wih0;
  const float* bb  = layer ? P.b1   : P.b0;
  const float* xin = layer ? gy0()  : gxseq();
  int Din = layer ? 256 : SEQD;
  const float* x = xin + t*Din;
  const float* Wr = Wih + ((size_t)d*512 + gate)*Din;
  float acc = 0.f;
  for (int k=lane; k<Din; k+=64) acc += x[k]*Wr[k];
  for (int off=32; off>0; off>>=1) acc += __shfl_down(acc, off);
  if (lane==0) gxg()[(t*2 + d)*512 + gate] = acc + bb[d*512 + gate];
}

// ---- LSTM recurrence only ----
__global__ void k_lstm_rec(Params P, int layer){
  int d = blockIdx.x, tid = threadIdx.x;      // 512 threads, 1 block per dir
  const float* Whh = layer ? P.Whh1 : P.Whh0;
  float* yout = layer ? gy1() : gy0();
  __shared__ float h[128], c[128], gbuf[512];
  if (tid < 128){ h[tid]=0.f; c[tid]=0.f; }
  __syncthreads();
  for (int s=0;s<2;s++){
    int t = (d==0) ? s : 1-s;
    float acc = gxg()[(t*2 + d)*512 + tid];
    const float* Ur = Whh + ((size_t)d*512 + tid)*128;
    for (int k=0;k<128;k++) acc += h[k]*Ur[k];
    gbuf[tid] = acc;
    __syncthreads();
    if (tid < 128){
      float ii = sigmf(gbuf[tid]);
      float ff = sigmf(gbuf[128+tid]);
      float gg = tanhf(gbuf[256+tid]);
      float oo = sigmf(gbuf[384+tid]);
      float cn = ff*c[tid] + ii*gg;
      c[tid] = cn;
      float hn = oo*tanhf(cn);
      h[tid] = hn;
      yout[t*256 + d*128 + tid] = hn;
    }
    __syncthreads();
  }
}

// ---------------- final FC + softmax ----------------
__global__ void k_final(Params P){
  int tid = threadIdx.x;
  __shared__ float sb[256], sb2[256];
  const float* x = gy1() + 256;  // x[-1]
  sb[tid]  = x[tid]*P.fc_w[tid*2+0];
  sb2[tid] = x[tid]*P.fc_w[tid*2+1];
  __syncthreads();
  for (int s=128;s>0;s>>=1){ if (tid<s){ sb[tid]+=sb[tid+s]; sb2[tid]+=sb2[tid+s]; } __syncthreads(); }
  if (tid==0){
    float l0 = sb[0] + P.fc_b[0];
    float l1 = sb2[0] + P.fc_b[1];
    float m = fmaxf(l0,l1);
    float e0 = expf(l0-m), e1 = expf(l1-m), inv = 1.f/(e0+e1);
    P.out[0] = e0*inv;
    P.out[1] = e1*inv;
  }
}

extern "C" void kernel_launch(void* const* d_in, const int* in_sizes, int n_in,
                              void* d_out, int out_size, void* d_ws, size_t ws_size,
                              hipStream_t stream){
  Params P;
  for (int g=0; g<2; ++g){
    int b = g*5;
    P.g[g].feat  = (const float*)d_in[b+0];
    P.g[g].eidx  = (const int*)d_in[b+1];
    P.g[g].eattr = (const float*)d_in[b+2];
    P.g[g].adj   = (const float*)d_in[b+3];
    P.g[g].n2n   = (const float*)d_in[b+4];
  }
  P.W_h   = (const float*)d_in[10];
  P.W_gat = (const float*)d_in[11];
  P.a_src = (const float*)d_in[12];
  P.a_dst = (const float*)d_in[13];
  P.a_e   = (const float*)d_in[14];
  P.We_gat= (const float*)d_in[15];
  P.W_out = (const float*)d_in[16];
  P.ao_src= (const float*)d_in[17];
  P.ao_dst= (const float*)d_in[18];
  P.ao_e  = (const float*)d_in[19];
  P.We_out= (const float*)d_in[20];
  P.ep1_w = (const float*)d_in[21];
  P.ep1_b = (const float*)d_in[22];
  P.ep2_w = (const float*)d_in[23];
  P.ep2_b = (const float*)d_in[24];
  P.g1_w  = (const float*)d_in[25];
  P.g1_b  = (const float*)d_in[26];
  P.g2_w  = (const float*)d_in[27];
  P.g2_b  = (const float*)d_in[28];
  P.g3_w  = (const float*)d_in[29];
  P.g3_b  = (const float*)d_in[30];
  P.Wih0  = (const float*)d_in[31];
  P.Whh0  = (const float*)d_in[32];
  P.b0    = (const float*)d_in[33];
  P.Wih1  = (const float*)d_in[34];
  P.Whh1  = (const float*)d_in[35];
  P.b1    = (const float*)d_in[36];
  P.fc_w  = (const float*)d_in[37];
  P.fc_b  = (const float*)d_in[38];
  P.out   = (float*)d_out;

  // ---- graph stages (both graphs in each kernel via grid dim) ----
  k_zero <<<dim3((TOTF+255)/256 + 1), 256, 0, stream>>>();
  k_pre  <<<dim3((NH*HID+CAT+255)/256), 256, 0, stream>>>(P);
  k_h0   <<<dim3((2*N*HID+255)/256), 256, 0, stream>>>(P);
  k_gpool_gate<<<dim3(N,2), 256, 0, stream>>>(P, OH0, HID, -1, P.g1_w, P.g1_b);
  k_gpool_out <<<dim3(2),   256, 0, stream>>>(P, OH0, HID, -1, 0);
  k_Wh   <<<dim3(N,NH,2), 128, 0, stream>>>(P);
  k_asad <<<dim3(NH,2),   256, 0, stream>>>(P);
  k_att1 <<<dim3(N,NH,2), 128, 0, stream>>>(P);
  k_edot1<<<dim3(E/TE1,2),128, 0, stream>>>(P);
  k_xw1  <<<dim3(N,2,2),  256, 0, stream>>>(P);
  k_s1   <<<dim3((E+255)/256,2), 256, 0, stream>>>(P);
  k_ns   <<<dim3(1,2),    256, 0, stream>>>(ODEG1, OSS1, ONS1);
  k_gpool_gate<<<dim3(N,2), 256, 0, stream>>>(P, OH1, CAT, ONS1, P.g2_w, P.g2_b);
  k_gpool_out <<<dim3(2),   256, 0, stream>>>(P, OH1, CAT, ONS1, HID);
  k_pairs<<<dim3((E+255)/256,2), 256, 0, stream>>>(P);
  k_Wh2  <<<dim3(N,2),    128, 0, stream>>>(P);
  k_asad2<<<dim3(2),      256, 0, stream>>>(P);
  k_att2 <<<dim3(N,2),    128, 0, stream>>>(P);
  k_e2f  <<<dim3(E/TE2,2),128, 0, stream>>>(P);
  k_xsd2 <<<dim3(2),      256, 0, stream>>>(P);
  k_s2   <<<dim3((E+255)/256,2), 256, 0, stream>>>(P);
  k_ns   <<<dim3(1,2),    256, 0, stream>>>(ODEG2, OSS2, ONS2);
  k_gpool_gate<<<dim3(N,2), 256, 0, stream>>>(P, OH2B, OUTD, ONS2, P.g3_w, P.g3_b);
  k_gpool_out <<<dim3(2),   256, 0, stream>>>(P, OH2B, OUTD, ONS2, HID+CAT);

  // ---- LSTM stack + classifier ----
  k_lstm_xg <<<dim3(512), 256, 0, stream>>>(P, 0);
  k_lstm_rec<<<dim3(2),   512, 0, stream>>>(P, 0);
  k_lstm_xg <<<dim3(512), 256, 0, stream>>>(P, 1);
  k_lstm_rec<<<dim3(2),   512, 0, stream>>>(P, 1);
  k_final<<<dim3(1), 256, 0, stream>>>(P);
}

// Round 7
// 672.702 us; speedup vs baseline: 3.6294x; 1.4178x over previous
//
#include <hip/hip_runtime.h>
#include <math.h>

#define DI static __device__ __forceinline__

DI float eluf(float x){ return x > 0.f ? x : expm1f(x); }
DI float lreluf(float x){ return x > 0.f ? x : 0.2f*x; }
DI float sigmf(float x){ return 1.f/(1.f+expf(-x)); }

constexpr int N=200, E=3200, HID=64, NH=16, OUTD=128, CAT=2048, SEQD=2240;

// ---- per-graph f32 scratch offsets (in floats) ----
constexpr int OH0   = 0;                 // [N,HID]   elu(feat@W_h)
constexpr int OWH   = OH0 + N*HID;       // [NH,N,OUTD] Wh per head
constexpr int OASN  = OWH + NH*N*OUTD;   // [NH,N]    Wh@a_src
constexpr int OADN  = OASN + NH*N;       // [NH,N]    Wh@a_dst
constexpr int OH1   = OADN + NH*N;       // [N,CAT]   concat head outputs
constexpr int OXW1  = OH1 + N*CAT;       // [N]
constexpr int OXW2  = OXW1 + 256;        // [N]
constexpr int OEW1  = OXW2 + 256;        // [E]
constexpr int OS1   = OEW1 + E;          // [E]
constexpr int ODEG1 = OS1 + E;           // [N]
constexpr int OSS1  = ODEG1 + 256;       // [N]
constexpr int ONS1  = OSS1 + 256;        // [N]
constexpr int OWH2  = ONS1 + 256;        // [N,OUTD]
constexpr int OAS2  = OWH2 + N*OUTD;     // [N]
constexpr int OAD2  = OAS2 + 256;        // [N]
constexpr int OEWV  = OAD2 + 256;        // [E]  RAW e1cat@v_e (atomic accum)
constexpr int OH2B  = OEWV + E;          // [N,OUTD]
constexpr int OXS2  = OH2B + N*OUTD;     // [N]
constexpr int OXD2  = OXS2 + 256;        // [N]
constexpr int OEW2  = OXD2 + 256;        // [E]
constexpr int OS2   = OEW2 + E;          // [E]
constexpr int ODEG2 = OS2 + E;           // [N]
constexpr int OSS2  = ODEG2 + 256;       // [N]
constexpr int ONS2  = OSS2 + 256;        // [N]
constexpr int OGATE = ONS2 + 256;        // [N]
constexpr int PGF   = OGATE + 256;       // per-graph float count
constexpr int GLOBF = 10624;
constexpr int TOTF  = GLOBF + 2*PGF;

// ---- static device scratch: independent of ws_size ----
__device__ float G_F[TOTF];
__device__ float G_E2ACC[2*E*OUTD];      // e2 pre-activation accumulator
__device__ int   G_PIDX[2*N*N];

DI float* gf(int g){ return G_F + GLOBF + (size_t)g*PGF; }
DI float* gwe_ae(){ return G_F; }
DI float* gv_e(){ return G_F + 1024; }
DI float* gy0(){ return G_F + 3072; }
DI float* gy1(){ return G_F + 3584; }
DI float* gxseq(){ return G_F + 4096; }
DI float* gxg(){ return G_F + 8576; }     // [t(2)][dir(2)][512]
DI int*   gpidx(int g){ return G_PIDX + g*N*N; }

struct GraphIn {
  const float *feat, *eattr, *adj, *n2n;
  const int   *eidx;
};

struct Params {
  GraphIn g[2];
  const float *W_h, *W_gat, *a_src, *a_dst, *a_e, *We_gat;
  const float *W_out, *ao_src, *ao_dst, *ao_e, *We_out;
  const float *ep1_w, *ep1_b, *ep2_w, *ep2_b;
  const float *g1_w, *g1_b, *g2_w, *g2_b, *g3_w, *g3_b;
  const float *Wih0, *Whh0, *b0, *Wih1, *Whh1, *b1, *fc_w, *fc_b;
  float *out;
};

// ---------------- zero ALL scratch; pairIdx=-1 ----------------
__global__ void k_zero(){
  int idx = blockIdx.x*256 + threadIdx.x;
  if (idx < TOTF) G_F[idx] = 0.f;
  if (idx < 2*E*OUTD) G_E2ACC[idx] = 0.f;
  if (idx < 2*N*N) G_PIDX[idx] = -1;
}

// ---------------- precontract We@a_e vectors ----------------
__global__ void k_pre(Params P){
  int idx = blockIdx.x*256 + threadIdx.x;
  if (idx < NH*HID){
    int h = idx/HID, c = idx%HID;
    const float* W = P.We_gat + (size_t)(h*HID + c)*OUTD;
    const float* a = P.a_e + h*OUTD;
    float acc = 0.f;
    for (int o=0;o<OUTD;o++) acc += W[o]*a[o];
    gwe_ae()[idx] = acc;
  } else if (idx < NH*HID + CAT){
    int c = idx - NH*HID;
    const float* W = P.We_out + (size_t)c*OUTD;
    float acc = 0.f;
    for (int o=0;o<OUTD;o++) acc += W[o]*P.ao_e[o];
    gv_e()[c] = acc;
  }
}

// ---------------- h0 = elu(feat @ W_h) ----------------
__global__ void k_h0(Params P){
  int idx = blockIdx.x*256 + threadIdx.x;
  if (idx >= 2*N*HID) return;
  int g = idx/(N*HID), r = idx%(N*HID), n = r/HID, c = r%HID;
  const float* feat = P.g[g].feat;
  float acc = 0.f;
  for (int k=0;k<HID;k++) acc += feat[n*HID+k]*P.W_h[k*HID+c];
  gf(g)[OH0 + n*HID + c] = eluf(acc);
}

// ---------------- Wh[h] = h0 @ W_gat[h] ----------------
__global__ void k_Wh(Params P){
  int n = blockIdx.x, h = blockIdx.y, g = blockIdx.z, o = threadIdx.x;
  __shared__ float hs[HID];
  float* f = gf(g);
  if (o < HID) hs[o] = f[OH0 + n*HID + o];
  __syncthreads();
  const float* W = P.W_gat + (size_t)h*HID*OUTD + o;
  float acc = 0.f;
  for (int c=0;c<HID;c++) acc += hs[c]*W[(size_t)c*OUTD];
  f[OWH + ((size_t)h*N + n)*OUTD + o] = acc;
}

// ---------------- asn/adn = Wh @ a_src / a_dst ----------------
__global__ void k_asad(Params P){
  int h = blockIdx.x, g = blockIdx.y;
  float* f = gf(g);
  for (int n = threadIdx.x; n < N; n += 256){
    const float* wh = f + OWH + ((size_t)h*N + n)*OUTD;
    float s=0.f, d=0.f;
    for (int o=0;o<OUTD;o++){
      float v = wh[o];
      s += v*P.a_src[h*OUTD+o];
      d += v*P.a_dst[h*OUTD+o];
    }
    f[OASN + h*N + n] = s;
    f[OADN + h*N + n] = d;
  }
}

// ---------------- GAT layer 1: row softmax + aggregate (per head) ----------------
__global__ void k_att1(Params P){
  int n = blockIdx.x, h = blockIdx.y, g = blockIdx.z, tid = threadIdx.x;
  __shared__ float z[N];
  __shared__ float red[128];
  float* f = gf(g);
  const float* adj = P.g[g].adj;
  const float* n2n = P.g[g].n2n;
  const float* weae = gwe_ae() + h*HID;
  float asn = f[OASN + h*N + n];
  const float* adn = f + OADN + h*N;
  for (int j = tid; j < N; j += 128){
    float a = adj[n*N + j];
    float zz;
    if (a > 0.f){
      const float* row = n2n + (size_t)(n*N + j)*HID;
      float ee = 0.f;
      for (int c=0;c<HID;c++) ee += row[c]*weae[c];
      zz = lreluf(asn + adn[j] + ee);
    } else zz = -1e9f;
    z[j] = zz;
  }
  __syncthreads();
  float m = -3e38f;
  for (int j = tid; j < N; j += 128) m = fmaxf(m, z[j]);
  red[tid] = m; __syncthreads();
  for (int s=64;s>0;s>>=1){ if (tid<s) red[tid]=fmaxf(red[tid],red[tid+s]); __syncthreads(); }
  m = red[0]; __syncthreads();
  float ssum = 0.f;
  for (int j = tid; j < N; j += 128){ float e = expf(z[j]-m); z[j]=e; ssum += e; }
  red[tid] = ssum; __syncthreads();
  for (int s=64;s>0;s>>=1){ if (tid<s) red[tid]+=red[tid+s]; __syncthreads(); }
  float inv = 1.f/red[0]; __syncthreads();
  const float* wh = f + OWH + (size_t)h*N*OUTD;
  float acc = 0.f;
  for (int j=0;j<N;j++){
    float w = z[j];
    if (w != 0.f) acc += w * wh[(size_t)j*OUTD + tid];
  }
  f[OH1 + (size_t)n*CAT + h*OUTD + tid] = eluf(acc*inv);
}

// ---- edge dots, head-split: partial ew1/ewv per (edge-tile, head), atomic ----
constexpr int TE1 = 8;
__global__ void k_edot1(Params P){
  int e0 = blockIdx.x*TE1, h = blockIdx.y, g = blockIdx.z, tid = threadIdx.x; // 128 thr
  __shared__ float es[TE1][HID];
  __shared__ float lred[2][TE1][2];
  const float* ea = P.g[g].eattr + (size_t)e0*HID;
  for (int i = tid; i < TE1*HID; i += 128) ((float*)es)[i] = ea[i];
  __syncthreads();
  const float* W = P.We_gat + (size_t)(h*HID)*OUTD + tid;
  float t[TE1];
  for (int e=0;e<TE1;e++) t[e]=0.f;
  for (int c=0;c<HID;c++){
    float w = W[(size_t)c*OUTD];
    for (int e=0;e<TE1;e++) t[e] += es[e][c]*w;
  }
  float w1 = P.ep1_w[2*CAT + h*OUTD + tid];
  float wv = gv_e()[h*OUTD + tid];
  int lane = tid & 63, wvi = tid >> 6;
  for (int e=0;e<TE1;e++){
    float u = eluf(t[e]);
    float v1 = u*w1, v2 = u*wv;
    for (int off=32;off>0;off>>=1){ v1 += __shfl_down(v1,off); v2 += __shfl_down(v2,off); }
    if (lane==0){ lred[wvi][e][0]=v1; lred[wvi][e][1]=v2; }
  }
  __syncthreads();
  if (tid < TE1*2){
    int e = tid>>1, which = tid&1;
    float s = lred[0][e][which]+lred[1][e][which];
    atomicAdd(&gf(g)[(which? OEWV:OEW1) + e0+e], s);
  }
}

// ---------------- pool1 node dots ----------------
__global__ void k_xw1(Params P){
  int n = blockIdx.x, wch = blockIdx.y, g = blockIdx.z, tid = threadIdx.x;
  __shared__ float sb[256];
  float* f = gf(g);
  const float* x = f + OH1 + (size_t)n*CAT;
  const float* w = P.ep1_w + wch*CAT;
  float acc = 0.f;
  for (int c = tid; c < CAT; c += 256) acc += x[c]*w[c];
  sb[tid] = acc; __syncthreads();
  for (int s=128;s>0;s>>=1){ if (tid<s) sb[tid]+=sb[tid+s]; __syncthreads(); }
  if (tid==0) f[(wch? OXW2:OXW1) + n] = sb[0];
}

// ---------------- pool1 edge scores + segment sums ----------------
__global__ void k_s1(Params P){
  int e = blockIdx.x*256 + threadIdx.x, g = blockIdx.y;
  if (e >= E) return;
  float* f = gf(g);
  const int* ei = P.g[g].eidx;
  int s = ei[e], d = ei[E+e];
  float v = sigmf(f[OXW1+s] + f[OXW2+d] + f[OEW1+e] + P.ep1_b[0]);
  f[OS1+e] = v;
  atomicAdd(&f[OSS1+s], v);
  atomicAdd(&f[ODEG1+s], 1.f);
}

__global__ void k_ns(int odeg, int oss, int ons){
  int g = blockIdx.y, n = threadIdx.x;
  if (n < N){ float* f = gf(g); f[ons+n] = f[oss+n]/(f[odeg+n]+1e-6f); }
}

// ---------------- pairIdx: last edge wins ----------------
__global__ void k_pairs(Params P){
  int e = blockIdx.x*256 + threadIdx.x, g = blockIdx.y;
  if (e >= E) return;
  const int* ei = P.g[g].eidx;
  atomicMax(&gpidx(g)[ei[e]*N + ei[E+e]], e);
}

// ---------------- global attention pool ----------------
__global__ void k_gpool_gate(Params P, int xoff, int D, int scaleoff, const float* w, const float* b){
  int n = blockIdx.x, g = blockIdx.y, tid = threadIdx.x;
  __shared__ float sb[256];
  float* f = gf(g);
  const float* x = f + xoff + (size_t)n*D;
  float acc = 0.f;
  for (int c = tid; c < D; c += 256) acc += x[c]*w[c];
  sb[tid] = acc; __syncthreads();
  for (int s=128;s>0;s>>=1){ if (tid<s) sb[tid]+=sb[tid+s]; __syncthreads(); }
  if (tid==0){
    float sc = scaleoff>=0 ? f[scaleoff+n] : 1.f;
    f[OGATE+n] = sigmf(sb[0]*sc + b[0]);
  }
}

__global__ void k_gpool_out(Params P, int xoff, int D, int scaleoff, int outoff){
  int g = blockIdx.x, tid = threadIdx.x;
  __shared__ float att[N];
  __shared__ float sb[256];
  float* f = gf(g);
  float m = -3e38f;
  for (int n = tid; n < N; n += 256) m = fmaxf(m, f[OGATE+n]);
  sb[tid] = m; __syncthreads();
  for (int s=128;s>0;s>>=1){ if (tid<s) sb[tid]=fmaxf(sb[tid],sb[tid+s]); __syncthreads(); }
  m = sb[0]; __syncthreads();
  float ss = 0.f;
  for (int n = tid; n < N; n += 256){ float e = expf(f[OGATE+n]-m); att[n]=e; ss += e; }
  sb[tid] = ss; __syncthreads();
  for (int s=128;s>0;s>>=1){ if (tid<s) sb[tid]+=sb[tid+s]; __syncthreads(); }
  float inv = 1.f/sb[0]; __syncthreads();
  for (int n = tid; n < N; n += 256){
    float sc = scaleoff>=0 ? f[scaleoff+n] : 1.f;
    att[n] *= inv*sc;
  }
  __syncthreads();
  const float* x = f + xoff;
  for (int c = tid; c < D; c += 256){
    float acc = 0.f;
    for (int n=0;n<N;n++) acc += att[n]*x[(size_t)n*D + c];
    gxseq()[g*SEQD + outoff + c] = acc;
  }
}

// ---------------- Wh2 = (h1cat @ W_out) * ns1 ----------------
__global__ void k_Wh2(Params P){
  int n = blockIdx.x, g = blockIdx.y, tid = threadIdx.x;
  __shared__ float hrow[128];
  float* f = gf(g);
  const float* x = f + OH1 + (size_t)n*CAT;
  float ns = f[ONS1+n];
  float acc = 0.f;
  for (int c0=0;c0<CAT;c0+=128){
    __syncthreads();
    hrow[tid] = x[c0+tid];
    __syncthreads();
    const float* W = P.W_out + (size_t)c0*OUTD + tid;
    for (int cc=0;cc<128;cc++) acc += hrow[cc]*W[(size_t)cc*OUTD];
  }
  f[OWH2 + (size_t)n*OUTD + tid] = acc*ns;
}

__global__ void k_asad2(Params P){
  int g = blockIdx.x;
  float* f = gf(g);
  for (int n = threadIdx.x; n < N; n += 256){
    const float* wh = f + OWH2 + (size_t)n*OUTD;
    float s=0.f, d=0.f;
    for (int o=0;o<OUTD;o++){
      float v = wh[o];
      s += v*P.ao_src[o];
      d += v*P.ao_dst[o];
    }
    f[OAS2+n]=s; f[OAD2+n]=d;
  }
}

// ---------------- GAT layer 2 ----------------
__global__ void k_att2(Params P){
  int n = blockIdx.x, g = blockIdx.y, tid = threadIdx.x;
  __shared__ float z[N];
  __shared__ float red[128];
  float* f = gf(g);
  const float* adj = P.g[g].adj;
  const int* pidx = gpidx(g);
  float asn = f[OAS2+n];
  const float* adn = f + OAD2;
  for (int j = tid; j < N; j += 128){
    float a = adj[n*N + j];
    float zz;
    if (a > 0.f){
      int p = pidx[n*N + j];
      float ee = (p >= 0) ? f[OEWV+p]*f[OS1+p] : 0.f;
      zz = lreluf(asn + adn[j] + ee);
    } else zz = -1e9f;
    z[j] = zz;
  }
  __syncthreads();
  float m = -3e38f;
  for (int j = tid; j < N; j += 128) m = fmaxf(m, z[j]);
  red[tid] = m; __syncthreads();
  for (int s=64;s>0;s>>=1){ if (tid<s) red[tid]=fmaxf(red[tid],red[tid+s]); __syncthreads(); }
  m = red[0]; __syncthreads();
  float ssum = 0.f;
  for (int j = tid; j < N; j += 128){ float e = expf(z[j]-m); z[j]=e; ssum += e; }
  red[tid] = ssum; __syncthreads();
  for (int s=64;s>0;s>>=1){ if (tid<s) red[tid]+=red[tid+s]; __syncthreads(); }
  float inv = 1.f/red[0]; __syncthreads();
  const float* wh = f + OWH2;
  float acc = 0.f;
  for (int j=0;j<N;j++){
    float w = z[j];
    if (w != 0.f) acc += w * wh[(size_t)j*OUTD + tid];
  }
  f[OH2B + (size_t)n*OUTD + tid] = acc*inv;   // concat=False: no elu
}

// ---- e2 partial: head-split second edge GEMM, atomic accum into G_E2ACC ----
constexpr int TE2 = 16;
__global__ void k_e2p(Params P){
  int e0 = blockIdx.x*TE2, h = blockIdx.y, g = blockIdx.z, tid = threadIdx.x; // 128 thr
  __shared__ float es[TE2][HID];       // 4KB
  __shared__ float tcol[TE2][OUTD];    // 8KB
  const float* ea = P.g[g].eattr + (size_t)e0*HID;
  for (int i = tid; i < TE2*HID; i += 128) ((float*)es)[i] = ea[i];
  __syncthreads();
  const float* W1 = P.We_gat + (size_t)(h*HID)*OUTD + tid;
  float t[TE2];
  for (int e=0;e<TE2;e++) t[e]=0.f;
  for (int c=0;c<HID;c++){
    float w = W1[(size_t)c*OUTD];
    for (int e=0;e<TE2;e++) t[e] += es[e][c]*w;
  }
  for (int e=0;e<TE2;e++) tcol[e][tid] = eluf(t[e]);
  __syncthreads();
  float acc[TE2];
  for (int e=0;e<TE2;e++) acc[e]=0.f;
  const float* W2 = P.We_out + (size_t)(h*OUTD)*OUTD + tid;
  for (int o=0;o<OUTD;o++){
    float w = W2[(size_t)o*OUTD];
    for (int e=0;e<TE2;e++) acc[e] += tcol[e][o]*w;
  }
  float* dst = G_E2ACC + ((size_t)g*E + e0)*OUTD + tid;
  for (int e=0;e<TE2;e++) atomicAdd(dst + (size_t)e*OUTD, acc[e]);
}

// ---- finish: ew2[e] = sum_col elu(s1*acc)*ep2_w[2C+col] ----
__global__ void k_ew2fin(Params P){
  int e0 = blockIdx.x*TE2, g = blockIdx.y, tid = threadIdx.x;  // 128 thr
  __shared__ float lred[2][TE2];
  float* f = gf(g);
  float w2 = P.ep2_w[2*OUTD + tid];
  const float* src = G_E2ACC + ((size_t)g*E + e0)*OUTD + tid;
  int lane = tid & 63, wvi = tid >> 6;
  for (int e=0;e<TE2;e++){
    float v = eluf(f[OS1+e0+e]*src[(size_t)e*OUTD]) * w2;
    for (int off=32;off>0;off>>=1) v += __shfl_down(v,off);
    if (lane==0) lred[wvi][e]=v;
  }
  __syncthreads();
  if (tid < TE2) f[OEW2+e0+tid] = lred[0][tid]+lred[1][tid];
}

// ---------------- pool2 node dots ----------------
__global__ void k_xsd2(Params P){
  int g = blockIdx.x;
  float* f = gf(g);
  for (int n = threadIdx.x; n < N; n += 256){
    const float* x = f + OH2B + (size_t)n*OUTD;
    float s=0.f, d=0.f;
    for (int k=0;k<OUTD;k++){
      float v = x[k];
      s += v*P.ep2_w[k];
      d += v*P.ep2_w[OUTD+k];
    }
    f[OXS2+n]=s; f[OXD2+n]=d;
  }
}

__global__ void k_s2(Params P){
  int e = blockIdx.x*256 + threadIdx.x, g = blockIdx.y;
  if (e >= E) return;
  float* f = gf(g);
  const int* ei = P.g[g].eidx;
  int s = ei[e], d = ei[E+e];
  float v = sigmf(f[OXS2+s] + f[OXD2+d] + f[OEW2+e] + P.ep2_b[0]);
  f[OS2+e] = v;
  atomicAdd(&f[OSS2+s], v);
  atomicAdd(&f[ODEG2+s], 1.f);
}

// ---- LSTM input projection: xg[t][d][512] = b + x[t] @ Wih[d]^T ----
__global__ void k_lstm_xg(Params P, int layer){
  int gid = blockIdx.x*4 + (threadIdx.x>>6);
  int lane = threadIdx.x & 63;
  int t = gid >> 10;
  int rem = gid & 1023;
  int d = rem >> 9;
  int gate = rem & 511;
  const float* Wih = layer ? P.Wih1 : P.Wih0;
  const float* bb  = layer ? P.b1   : P.b0;
  const float* xin = layer ? gy0()  : gxseq();
  int Din = layer ? 256 : SEQD;
  const float* x = xin + t*Din;
  const float* Wr = Wih + ((size_t)d*512 + gate)*Din;
  float acc = 0.f;
  for (int k=lane; k<Din; k+=64) acc += x[k]*Wr[k];
  for (int off=32; off>0; off>>=1) acc += __shfl_down(acc, off);
  if (lane==0) gxg()[(t*2 + d)*512 + gate] = acc + bb[d*512 + gate];
}

// ---- LSTM recurrence only ----
__global__ void k_lstm_rec(Params P, int layer){
  int d = blockIdx.x, tid = threadIdx.x;      // 512 threads, 1 block per dir
  const float* Whh = layer ? P.Whh1 : P.Whh0;
  float* yout = layer ? gy1() : gy0();
  __shared__ float h[128], c[128], gbuf[512];
  if (tid < 128){ h[tid]=0.f; c[tid]=0.f; }
  __syncthreads();
  for (int s=0;s<2;s++){
    int t = (d==0) ? s : 1-s;
    float acc = gxg()[(t*2 + d)*512 + tid];
    const float* Ur = Whh + ((size_t)d*512 + tid)*128;
    for (int k=0;k<128;k++) acc += h[k]*Ur[k];
    gbuf[tid] = acc;
    __syncthreads();
    if (tid < 128){
      float ii = sigmf(gbuf[tid]);
      float ff = sigmf(gbuf[128+tid]);
      float gg = tanhf(gbuf[256+tid]);
      float oo = sigmf(gbuf[384+tid]);
      float cn = ff*c[tid] + ii*gg;
      c[tid] = cn;
      float hn = oo*tanhf(cn);
      h[tid] = hn;
      yout[t*256 + d*128 + tid] = hn;
    }
    __syncthreads();
  }
}

// ---------------- final FC + softmax ----------------
__global__ void k_final(Params P){
  int tid = threadIdx.x;
  __shared__ float sb[256], sb2[256];
  const float* x = gy1() + 256;  // x[-1]
  sb[tid]  = x[tid]*P.fc_w[tid*2+0];
  sb2[tid] = x[tid]*P.fc_w[tid*2+1];
  __syncthreads();
  for (int s=128;s>0;s>>=1){ if (tid<s){ sb[tid]+=sb[tid+s]; sb2[tid]+=sb2[tid+s]; } __syncthreads(); }
  if (tid==0){
    float l0 = sb[0] + P.fc_b[0];
    float l1 = sb2[0] + P.fc_b[1];
    float m = fmaxf(l0,l1);
    float e0 = expf(l0-m), e1 = expf(l1-m), inv = 1.f/(e0+e1);
    P.out[0] = e0*inv;
    P.out[1] = e1*inv;
  }
}

extern "C" void kernel_launch(void* const* d_in, const int* in_sizes, int n_in,
                              void* d_out, int out_size, void* d_ws, size_t ws_size,
                              hipStream_t stream){
  Params P;
  for (int g=0; g<2; ++g){
    int b = g*5;
    P.g[g].feat  = (const float*)d_in[b+0];
    P.g[g].eidx  = (const int*)d_in[b+1];
    P.g[g].eattr = (const float*)d_in[b+2];
    P.g[g].adj   = (const float*)d_in[b+3];
    P.g[g].n2n   = (const float*)d_in[b+4];
  }
  P.W_h   = (const float*)d_in[10];
  P.W_gat = (const float*)d_in[11];
  P.a_src = (const float*)d_in[12];
  P.a_dst = (const float*)d_in[13];
  P.a_e   = (const float*)d_in[14];
  P.We_gat= (const float*)d_in[15];
  P.W_out = (const float*)d_in[16];
  P.ao_src= (const float*)d_in[17];
  P.ao_dst= (const float*)d_in[18];
  P.ao_e  = (const float*)d_in[19];
  P.We_out= (const float*)d_in[20];
  P.ep1_w = (const float*)d_in[21];
  P.ep1_b = (const float*)d_in[22];
  P.ep2_w = (const float*)d_in[23];
  P.ep2_b = (const float*)d_in[24];
  P.g1_w  = (const float*)d_in[25];
  P.g1_b  = (const float*)d_in[26];
  P.g2_w  = (const float*)d_in[27];
  P.g2_b  = (const float*)d_in[28];
  P.g3_w  = (const float*)d_in[29];
  P.g3_b  = (const float*)d_in[30];
  P.Wih0  = (const float*)d_in[31];
  P.Whh0  = (const float*)d_in[32];
  P.b0    = (const float*)d_in[33];
  P.Wih1  = (const float*)d_in[34];
  P.Whh1  = (const float*)d_in[35];
  P.b1    = (const float*)d_in[36];
  P.fc_w  = (const float*)d_in[37];
  P.fc_b  = (const float*)d_in[38];
  P.out   = (float*)d_out;

  // ---- graph stages (both graphs in each kernel via grid dim) ----
  k_zero <<<dim3((TOTF+255)/256 + 1), 256, 0, stream>>>();
  k_pre  <<<dim3((NH*HID+CAT+255)/256), 256, 0, stream>>>(P);
  k_h0   <<<dim3((2*N*HID+255)/256), 256, 0, stream>>>(P);
  k_gpool_gate<<<dim3(N,2), 256, 0, stream>>>(P, OH0, HID, -1, P.g1_w, P.g1_b);
  k_gpool_out <<<dim3(2),   256, 0, stream>>>(P, OH0, HID, -1, 0);
  k_Wh   <<<dim3(N,NH,2), 128, 0, stream>>>(P);
  k_asad <<<dim3(NH,2),   256, 0, stream>>>(P);
  k_att1 <<<dim3(N,NH,2), 128, 0, stream>>>(P);
  k_edot1<<<dim3(E/TE1,NH,2),128, 0, stream>>>(P);
  k_xw1  <<<dim3(N,2,2),  256, 0, stream>>>(P);
  k_s1   <<<dim3((E+255)/256,2), 256, 0, stream>>>(P);
  k_ns   <<<dim3(1,2),    256, 0, stream>>>(ODEG1, OSS1, ONS1);
  k_gpool_gate<<<dim3(N,2), 256, 0, stream>>>(P, OH1, CAT, ONS1, P.g2_w, P.g2_b);
  k_gpool_out <<<dim3(2),   256, 0, stream>>>(P, OH1, CAT, ONS1, HID);
  k_pairs<<<dim3((E+255)/256,2), 256, 0, stream>>>(P);
  k_Wh2  <<<dim3(N,2),    128, 0, stream>>>(P);
  k_asad2<<<dim3(2),      256, 0, stream>>>(P);
  k_att2 <<<dim3(N,2),    128, 0, stream>>>(P);
  k_e2p  <<<dim3(E/TE2,NH,2),128, 0, stream>>>(P);
  k_ew2fin<<<dim3(E/TE2,2),128, 0, stream>>>(P);
  k_xsd2 <<<dim3(2),      256, 0, stream>>>(P);
  k_s2   <<<dim3((E+255)/256,2), 256, 0, stream>>>(P);
  k_ns   <<<dim3(1,2),    256, 0, stream>>>(ODEG2, OSS2, ONS2);
  k_gpool_gate<<<dim3(N,2), 256, 0, stream>>>(P, OH2B, OUTD, ONS2, P.g3_w, P.g3_b);
  k_gpool_out <<<dim3(2),   256, 0, stream>>>(P, OH2B, OUTD, ONS2, HID+CAT);

  // ---- LSTM stack + classifier ----
  k_lstm_xg <<<dim3(512), 256, 0, stream>>>(P, 0);
  k_lstm_rec<<<dim3(2),   512, 0, stream>>>(P, 0);
  k_lstm_xg <<<dim3(512), 256, 0, stream>>>(P, 1);
  k_lstm_rec<<<dim3(2),   512, 0, stream>>>(P, 1);
  k_final<<<dim3(1), 256, 0, stream>>>(P);
}